// Round 9
// baseline (724.671 us; speedup 1.0000x reference)
//
#include <hip/hip_runtime.h>

#define FD   128        // feature dim (floats)
#define FDH  64         // pairs per row (bf16x2 uints / fp8x2 ushorts)
#define EPSN 1e-8f
#define RCC  0.5f
#define SCAN_TPB 256
#define SCAN_ELEMS 1024

typedef unsigned int uint;
typedef unsigned short u16;
typedef float fx2 __attribute__((ext_vector_type(2)));

__device__ __forceinline__ float wave_sum(float x) {
#pragma unroll
    for (int off = 32; off > 0; off >>= 1) x += __shfl_xor(x, off);
    return x;
}

__device__ __forceinline__ uint packbf2(float a, float b) {
    uint ua = __float_as_uint(a); ua += 0x7fffu + ((ua >> 16) & 1u);
    uint ub = __float_as_uint(b); ub += 0x7fffu + ((ub >> 16) & 1u);
    return (ua >> 16) | (ub & 0xffff0000u);
}
__device__ __forceinline__ float2 unpackbf2(uint v) {
    return make_float2(__uint_as_float(v << 16), __uint_as_float(v & 0xffff0000u));
}
__device__ __forceinline__ fx2 unpackfp8(uint v) {        // 2x OCP e4m3 -> 2x f32
    return __builtin_amdgcn_cvt_pk_f32_fp8((int)v, false);
}
__device__ __forceinline__ u16 packfp8(float a, float b) { // 2x f32 -> 2x OCP e4m3
    return (u16)__builtin_amdgcn_cvt_pk_fp8_f32(a, b, 0, false);
}

// ---------------- Pass A: linked-list insert (1 atomicExch per insertion) + fused prep ----
// slot layout: UB edge e -> slots 2e,2e+1 ; UI edge f -> 2E_UB+2f,+1 ; BI edge g -> 2E_UB+2E_UI+g
__global__ void passA(const int* __restrict__ ub_u, const int* __restrict__ ub_b,
                      const int* __restrict__ ui_u, const int* __restrict__ ui_i,
                      const int* __restrict__ bi_b, const int* __restrict__ bi_i,
                      const float* __restrict__ uf, const float* __restrict__ bf,
                      const float* __restrict__ itf,
                      int E_UB, int E_UI, int E_BI, int NU, int NB, int n1, int n2, int NT,
                      int nblk_edges,
                      int* __restrict__ head, int2* __restrict__ pairLL,
                      uint* __restrict__ fini16, float* __restrict__ normf) {
    if ((int)blockIdx.x < nblk_edges) {
        int e = blockIdx.x * blockDim.x + threadIdx.x;
        if (e < E_UB) {
            int a = ub_u[e], b = ub_b[e] + NU;
            int s0 = 2 * e;
            int p0 = atomicExch(&head[a], s0);
            int p1 = atomicExch(&head[b], s0 + 1);
            ((int4*)pairLL)[e] = make_int4(p0, b, p1, a);
        } else if (e < E_UB + E_UI) {
            int f = e - E_UB;
            int a = ui_u[f], bl = ui_i[f] + NU;     // graph-local col ids
            int s0 = 2 * E_UB + 2 * f;
            int p0 = atomicExch(&head[n1 + a], s0);
            int p1 = atomicExch(&head[n1 + bl], s0 + 1);
            ((int4*)pairLL)[E_UB + f] = make_int4(p0, bl, p1, a);
        } else if (e < E_UB + E_UI + E_BI) {
            int g = e - E_UB - E_UI;
            int s = 2 * E_UB + 2 * E_UI + g;
            int p = atomicExch(&head[n1 + n2 + bi_b[g]], s);
            pairLL[s] = make_int2(p, bi_i[g]);
        }
    } else {
        int w = (((int)blockIdx.x - nblk_edges) * blockDim.x + threadIdx.x) >> 6;
        int lane = threadIdx.x & 63;
        if (w >= NT) return;
        const float* src = (w < NU) ? uf + (size_t)w * FD
                         : (w < NU + NB) ? bf + (size_t)(w - NU) * FD
                         : itf + (size_t)(w - NU - NB) * FD;
        float2 x = ((const float2*)src)[lane];
        float ss = wave_sum(x.x * x.x + x.y * x.y);
        float nrm = sqrtf(ss);
        float inv = 1.0f / fmaxf(nrm, 1e-12f);
        fini16[(size_t)w * FDH + lane] = packbf2(x.x * inv, x.y * inv);
        if (lane == 0) normf[w] = nrm;
    }
}

// ---------------- Pass B: chain length -> deg, dinv ----------------
__global__ void passB(const int* __restrict__ head, const int2* __restrict__ pairLL,
                      int NN, int n12, int* __restrict__ deg, float* __restrict__ dinv) {
    int r = blockIdx.x * blockDim.x + threadIdx.x;
    if (r > NN) return;
    if (r == NN) { deg[NN] = 0; return; }
    int c = 0;
    int s = head[r];
    while (s >= 0) { c++; s = pairLL[s].x; }
    deg[r] = c;
    if (r < n12) dinv[r] = 1.0f / (sqrtf((float)c) + EPSN);
}

// ---------------- conv_g8: g8[r] = fp8(fini[node(r)] * dinv[r] * norm[node(r)]) ------
__global__ void conv_g8(const uint* __restrict__ fini16, const float* __restrict__ normf,
                        const float* __restrict__ dinv,
                        int n1, int NU, int NB, int n12, u16* __restrict__ g8) {
    int w = (blockIdx.x * blockDim.x + threadIdx.x) >> 6;
    int lane = threadIdx.x & 63;
    if (w >= n12) return;
    int node = (w < n1) ? w : ((w - n1 < NU) ? (w - n1) : (w - n1 + NB));
    float sc = dinv[w] * normf[node];
    float2 f = unpackbf2(fini16[(size_t)node * FDH + lane]);
    g8[(size_t)w * FDH + lane] = packfp8(f.x * sc, f.y * sc);
}

// ---------------- exclusive scan ----------------
__global__ void scan_a(const int* __restrict__ in, int* __restrict__ out,
                       int* __restrict__ bsum, int nelem) {
    __shared__ int tsum[SCAN_TPB];
    int tid = threadIdx.x;
    int base = blockIdx.x * SCAN_ELEMS + tid * 4;
    int v0 = (base + 0 < nelem) ? in[base + 0] : 0;
    int v1 = (base + 1 < nelem) ? in[base + 1] : 0;
    int v2 = (base + 2 < nelem) ? in[base + 2] : 0;
    int v3 = (base + 3 < nelem) ? in[base + 3] : 0;
    int s = v0 + v1 + v2 + v3;
    tsum[tid] = s;
    __syncthreads();
    for (int off = 1; off < SCAN_TPB; off <<= 1) {
        int y = (tid >= off) ? tsum[tid - off] : 0;
        __syncthreads();
        tsum[tid] += y;
        __syncthreads();
    }
    int excl = tsum[tid] - s;
    if (tid == SCAN_TPB - 1) bsum[blockIdx.x] = tsum[SCAN_TPB - 1];
    if (base + 0 < nelem) out[base + 0] = excl;
    excl += v0;
    if (base + 1 < nelem) out[base + 1] = excl;
    excl += v1;
    if (base + 2 < nelem) out[base + 2] = excl;
    excl += v2;
    if (base + 3 < nelem) out[base + 3] = excl;
}

__global__ void scan_b(int* __restrict__ bsum, int nb) {   // nb <= 512
    __shared__ int sm[512];
    int tid = threadIdx.x;
    int v = (tid < nb) ? bsum[tid] : 0;
    sm[tid] = v;
    __syncthreads();
    for (int off = 1; off < 512; off <<= 1) {
        int y = (tid >= off) ? sm[tid - off] : 0;
        __syncthreads();
        sm[tid] += y;
        __syncthreads();
    }
    if (tid < nb) bsum[tid] = sm[tid] - v;
}

__global__ void scan_c(int* __restrict__ out, const int* __restrict__ bsum, int nelem) {
    int base = blockIdx.x * SCAN_ELEMS + threadIdx.x * 4;
    int add = bsum[blockIdx.x];
#pragma unroll
    for (int k = 0; k < 4; ++k)
        if (base + k < nelem) out[base + k] += add;
}

// ---------------- Pass C: flatten chains to CSR ----------------
__global__ void passC(const int* __restrict__ head, const int2* __restrict__ pairLL,
                      const int* __restrict__ rowptr, const float* __restrict__ bi_vals,
                      int NN, int n12, int S1,
                      int* __restrict__ cols, float* __restrict__ wts) {
    int r = blockIdx.x * blockDim.x + threadIdx.x;
    if (r >= NN) return;
    int pos = rowptr[r];
    int s = head[r];
    if (r < n12) {
        while (s >= 0) { int2 p = pairLL[s]; cols[pos++] = p.y; s = p.x; }
    } else {
        while (s >= 0) {
            int2 p = pairLL[s];
            cols[pos] = p.y;
            wts[pos - S1] = bi_vals[s - S1];
            pos++; s = p.x;
        }
    }
}

// ---------------- Layer 1: pure gather of pre-scaled fp8 g8 ----------------
// sum = dr * SUM g8[c]; v = (sum + RCC*i0)*0.5, l2norm
// facc16 = bf16(i0*norm + v); fX8 = fp8(v*dr)
__global__ void spmm_L1(const int* __restrict__ rowptr, const int* __restrict__ cols,
                        const float* __restrict__ dinv, const float* __restrict__ normf,
                        const uint* __restrict__ fini16, const u16* __restrict__ g8,
                        uint* __restrict__ facc16, u16* __restrict__ fX8,
                        int n1, int NU, int NB, int n12) {
    int w = (blockIdx.x * blockDim.x + threadIdx.x) >> 6;
    int lane = threadIdx.x & 63;
    if (w >= n12) return;
    int s = rowptr[w], e = rowptr[w + 1];
    bool ui = (w >= n1);
    int sB = ui ? n1 : 0;
    int node = ui ? ((w - n1 < NU) ? (w - n1) : (w - n1 + NB)) : w;
    float dr = dinv[w];
    const u16* tab = g8 + (size_t)sB * FDH + lane;
    float ax = 0.0f, ay = 0.0f;
    int j = s;
    for (; j + 4 <= e; j += 4) {
        int c0 = cols[j], c1 = cols[j + 1], c2 = cols[j + 2], c3 = cols[j + 3];
        uint x0 = tab[(size_t)c0 * FDH];
        uint x1 = tab[(size_t)c1 * FDH];
        uint x2 = tab[(size_t)c2 * FDH];
        uint x3 = tab[(size_t)c3 * FDH];
        fx2 f0 = unpackfp8(x0), f1 = unpackfp8(x1);
        fx2 f2 = unpackfp8(x2), f3 = unpackfp8(x3);
        ax += f0.x + f1.x + f2.x + f3.x;
        ay += f0.y + f1.y + f2.y + f3.y;
    }
    for (; j < e; ++j) {
        fx2 f0 = unpackfp8(tab[(size_t)cols[j] * FDH]);
        ax += f0.x; ay += f0.y;
    }
    float2 i0 = unpackbf2(fini16[(size_t)node * FDH + lane]);
    float vx = (dr * ax + RCC * i0.x) * 0.5f;
    float vy = (dr * ay + RCC * i0.y) * 0.5f;
    float ss = wave_sum(vx * vx + vy * vy);
    float inv = 1.0f / fmaxf(sqrtf(ss), 1e-12f);
    vx *= inv; vy *= inv;
    float nr = normf[node];
    facc16[(size_t)w * FDH + lane] = packbf2(fmaf(i0.x, nr, vx), fmaf(i0.y, nr, vy));
    fX8[(size_t)w * FDH + lane] = packfp8(vx * dr, vy * dr);
}

// ---------------- Layer 2: pure gather from pre-scaled fp8 fX8 --------------
// v2 = (dr*sum + RCC*i0)/3, l2norm; an = facc16 + v2 -> out / items16
__global__ void spmm_L2(const int* __restrict__ rowptr, const int* __restrict__ cols,
                        const float* __restrict__ dinv, const uint* __restrict__ fini16,
                        const uint* __restrict__ facc16, const u16* __restrict__ fX8,
                        uint* __restrict__ items16, float* __restrict__ outp,
                        int n1, int NU, int NB, int n12) {
    int w = (blockIdx.x * blockDim.x + threadIdx.x) >> 6;
    int lane = threadIdx.x & 63;
    if (w >= n12) return;
    int s = rowptr[w], e = rowptr[w + 1];
    bool ui = (w >= n1);
    int sB = ui ? n1 : 0;
    int node = ui ? ((w - n1 < NU) ? (w - n1) : (w - n1 + NB)) : w;
    float dr = dinv[w];
    const u16* tab = fX8 + (size_t)sB * FDH + lane;
    float ax = 0.0f, ay = 0.0f;
    int j = s;
    for (; j + 4 <= e; j += 4) {
        int c0 = cols[j], c1 = cols[j + 1], c2 = cols[j + 2], c3 = cols[j + 3];
        uint x0 = tab[(size_t)c0 * FDH];
        uint x1 = tab[(size_t)c1 * FDH];
        uint x2 = tab[(size_t)c2 * FDH];
        uint x3 = tab[(size_t)c3 * FDH];
        fx2 f0 = unpackfp8(x0), f1 = unpackfp8(x1);
        fx2 f2 = unpackfp8(x2), f3 = unpackfp8(x3);
        ax += f0.x + f1.x + f2.x + f3.x;
        ay += f0.y + f1.y + f2.y + f3.y;
    }
    for (; j < e; ++j) {
        fx2 f0 = unpackfp8(tab[(size_t)cols[j] * FDH]);
        ax += f0.x; ay += f0.y;
    }
    float2 i0 = unpackbf2(fini16[(size_t)node * FDH + lane]);
    float vx = (dr * ax + RCC * i0.x) * (1.0f / 3.0f);
    float vy = (dr * ay + RCC * i0.y) * (1.0f / 3.0f);
    float ss = wave_sum(vx * vx + vy * vy);
    float inv = 1.0f / fmaxf(sqrtf(ss), 1e-12f);
    vx *= inv; vy *= inv;
    float2 a0 = unpackbf2(facc16[(size_t)w * FDH + lane]);
    float anx = a0.x + vx, any = a0.y + vy;
    if (!ui) {
        size_t dst = (w < NU) ? (size_t)(NU + w) : (size_t)(2 * NU + NB + (w - NU));
        ((float2*)(outp + dst * FD))[lane] = make_float2(anx, any);
    } else {
        int l = w - n1;
        if (l < NU) ((float2*)(outp + (size_t)l * FD))[lane] = make_float2(anx, any);
        else        items16[(size_t)(l - NU) * FDH + lane] = packbf2(anx, any);
    }
}

// ---------------- BI gather from bf16 items ----------------
__global__ void bi_gather(const int* __restrict__ rowptr, const int* __restrict__ cols,
                          const float* __restrict__ wts, int S1,
                          const uint* __restrict__ items16,
                          float* __restrict__ outb, int nb) {
    int w = (blockIdx.x * blockDim.x + threadIdx.x) >> 6;
    int lane = threadIdx.x & 63;
    if (w >= nb) return;
    int s = rowptr[w], e = rowptr[w + 1];
    float ax = 0.0f, ay = 0.0f;
    int j = s;
    for (; j + 4 <= e; j += 4) {
        int c0 = cols[j], c1 = cols[j + 1], c2 = cols[j + 2], c3 = cols[j + 3];
        float w0 = wts[j - S1], w1 = wts[j + 1 - S1];
        float w2 = wts[j + 2 - S1], w3 = wts[j + 3 - S1];
        uint x0 = items16[(size_t)c0 * FDH + lane];
        uint x1 = items16[(size_t)c1 * FDH + lane];
        uint x2 = items16[(size_t)c2 * FDH + lane];
        uint x3 = items16[(size_t)c3 * FDH + lane];
        float2 f0 = unpackbf2(x0), f1 = unpackbf2(x1);
        float2 f2 = unpackbf2(x2), f3 = unpackbf2(x3);
        ax = fmaf(w0, f0.x, ax); ay = fmaf(w0, f0.y, ay);
        ax = fmaf(w1, f1.x, ax); ay = fmaf(w1, f1.y, ay);
        ax = fmaf(w2, f2.x, ax); ay = fmaf(w2, f2.y, ay);
        ax = fmaf(w3, f3.x, ax); ay = fmaf(w3, f3.y, ay);
    }
    for (; j < e; ++j) {
        float w0 = wts[j - S1];
        float2 f0 = unpackbf2(items16[(size_t)cols[j] * FDH + lane]);
        ax = fmaf(w0, f0.x, ax); ay = fmaf(w0, f0.y, ay);
    }
    ((float2*)(outb + (size_t)w * FD))[lane] = make_float2(ax, ay);
}

extern "C" void kernel_launch(void* const* d_in, const int* in_sizes, int n_in,
                              void* d_out, int out_size, void* d_ws, size_t ws_size,
                              hipStream_t stream) {
    const float* users   = (const float*)d_in[0];
    const float* bundles = (const float*)d_in[1];
    const float* items   = (const float*)d_in[2];
    const float* bi_vals = (const float*)d_in[3];
    const int* ub_u = (const int*)d_in[4];
    const int* ub_b = (const int*)d_in[5];
    const int* ui_u = (const int*)d_in[6];
    const int* ui_i = (const int*)d_in[7];
    const int* bi_b = (const int*)d_in[8];
    const int* bi_i = (const int*)d_in[9];

    const int NU = in_sizes[0] / FD;
    const int NB = in_sizes[1] / FD;
    const int NI = in_sizes[2] / FD;
    const int E_BI = in_sizes[3];
    const int E_UB = in_sizes[4];
    const int E_UI = in_sizes[6];
    float* out = (float*)d_out;

    const int n1 = NU + NB, n2 = NU + NI;
    const int n12 = n1 + n2;
    const int NT = NU + NB + NI;
    const int NN = n12 + NB;                        // total CSR rows
    const int S1 = 2 * E_UB + 2 * E_UI;             // first BI slot / BI rowptr base
    const int TOT = S1 + E_BI;                      // total CSR entries
    const int ETOT = E_UB + E_UI + E_BI;

    // ---- workspace layout ----
    uint* fini16   = (uint*)d_ws;                          // NT*FDH uints
    uint* facc16   = fini16 + (size_t)NT * FDH;            // n12*FDH uints
    uint* items16  = facc16 + (size_t)n12 * FDH;           // NI*FDH uints
    u16* g8        = (u16*)(items16 + (size_t)NI * FDH);   // n12*FDH u16
    u16* fX8       = g8 + (size_t)n12 * FDH;               // n12*FDH u16
    float* normf   = (float*)(fX8 + (size_t)n12 * FDH);    // NT
    float* dinv    = normf + NT;                           // n12
    float* wts     = dinv + n12;                           // E_BI
    int* deg       = (int*)(wts + E_BI);                   // NN+1
    int* rowptr    = deg + (NN + 1);                       // NN+1
    int* head      = rowptr + (NN + 1);                    // NN
    int* bsum      = head + NN;                            // 512
    int* cols      = bsum + 512;                           // TOT
    int2* pairLL   = (int2*)((((size_t)(cols + TOT)) + 15) & ~(size_t)15);  // TOT int2

    dim3 blk(256);
    auto rows_grid = [](int n) { return dim3((unsigned)((n + 3) / 4)); };
    auto thr_grid  = [](int n) { return dim3((unsigned)((n + 255) / 256)); };

    // ---- linked-list CSR build (one atomic pass) + fused feature prep ----
    hipMemsetAsync(head, 0xFF, (size_t)NN * 4, stream);    // head = -1
    int nblk_edges = (ETOT + 255) / 256;
    int nblk_prep  = (NT + 3) / 4;
    passA<<<dim3((unsigned)(nblk_edges + nblk_prep)), blk, 0, stream>>>(
        ub_u, ub_b, ui_u, ui_i, bi_b, bi_i, users, bundles, items,
        E_UB, E_UI, E_BI, NU, NB, n1, n2, NT, nblk_edges,
        head, pairLL, fini16, normf);
    passB<<<thr_grid(NN + 1), blk, 0, stream>>>(head, pairLL, NN, n12, deg, dinv);
    conv_g8<<<rows_grid(n12), blk, 0, stream>>>(fini16, normf, dinv, n1, NU, NB, n12, g8);
    {
        int nelem = NN + 1;
        int nblk = (nelem + SCAN_ELEMS - 1) / SCAN_ELEMS;
        scan_a<<<dim3((unsigned)nblk), dim3(SCAN_TPB), 0, stream>>>(deg, rowptr, bsum, nelem);
        scan_b<<<dim3(1), dim3(512), 0, stream>>>(bsum, nblk);
        scan_c<<<dim3((unsigned)nblk), dim3(SCAN_TPB), 0, stream>>>(rowptr, bsum, nelem);
    }
    passC<<<thr_grid(NN), blk, 0, stream>>>(head, pairLL, rowptr, bi_vals,
                                            NN, n12, S1, cols, wts);

    // ---- Layer 1 (UB + UI fused, fp8 gather) ----
    spmm_L1<<<rows_grid(n12), blk, 0, stream>>>(rowptr, cols, dinv, normf,
                                                fini16, g8, facc16, fX8, n1, NU, NB, n12);
    // ---- Layer 2 (UB + UI fused, fp8 gather) + writeout ----
    spmm_L2<<<rows_grid(n12), blk, 0, stream>>>(rowptr, cols, dinv, fini16,
                                                facc16, fX8, items16, out, n1, NU, NB, n12);
    // ---- BI aggregation ----
    bi_gather<<<rows_grid(NB), blk, 0, stream>>>(rowptr + n12, cols, wts, S1, items16,
        out + (size_t)2 * NU * FD, NB);
}

// Round 10
// 718.215 us; speedup vs baseline: 1.0090x; 1.0090x over previous
//
#include <hip/hip_runtime.h>

#define FD   128        // feature dim (floats)
#define FDH  64         // uints per bf16 row / u16s per fp8 row
#define EPSN 1e-8f
#define RCC  0.5f
#define SCAN_TPB 256
#define SCAN_ELEMS 1024

typedef unsigned int uint;
typedef unsigned short u16;
typedef unsigned char u8;
typedef float fx2 __attribute__((ext_vector_type(2)));

__device__ __forceinline__ float wave_sum(float x) {
#pragma unroll
    for (int off = 32; off > 0; off >>= 1) x += __shfl_xor(x, off);
    return x;
}

__device__ __forceinline__ uint packbf2(float a, float b) {
    uint ua = __float_as_uint(a); ua += 0x7fffu + ((ua >> 16) & 1u);
    uint ub = __float_as_uint(b); ub += 0x7fffu + ((ub >> 16) & 1u);
    return (ua >> 16) | (ub & 0xffff0000u);
}
__device__ __forceinline__ float2 unpackbf2(uint v) {
    return make_float2(__uint_as_float(v << 16), __uint_as_float(v & 0xffff0000u));
}
__device__ __forceinline__ u16 packfp8(float a, float b) { // 2x f32 -> 2x OCP e4m3
    return (u16)__builtin_amdgcn_cvt_pk_fp8_f32(a, b, 0, false);
}

// ---------------- Pass A: linked-list insert (1 atomicExch per insertion) + fused prep ----
__global__ void passA(const int* __restrict__ ub_u, const int* __restrict__ ub_b,
                      const int* __restrict__ ui_u, const int* __restrict__ ui_i,
                      const int* __restrict__ bi_b, const int* __restrict__ bi_i,
                      const float* __restrict__ uf, const float* __restrict__ bf,
                      const float* __restrict__ itf,
                      int E_UB, int E_UI, int E_BI, int NU, int NB, int n1, int n2, int NT,
                      int nblk_edges,
                      int* __restrict__ head, int2* __restrict__ pairLL,
                      uint* __restrict__ fini16, float* __restrict__ normf) {
    if ((int)blockIdx.x < nblk_edges) {
        int e = blockIdx.x * blockDim.x + threadIdx.x;
        if (e < E_UB) {
            int a = ub_u[e], b = ub_b[e] + NU;
            int s0 = 2 * e;
            int p0 = atomicExch(&head[a], s0);
            int p1 = atomicExch(&head[b], s0 + 1);
            ((int4*)pairLL)[e] = make_int4(p0, b, p1, a);
        } else if (e < E_UB + E_UI) {
            int f = e - E_UB;
            int a = ui_u[f], bl = ui_i[f] + NU;     // graph-local col ids
            int s0 = 2 * E_UB + 2 * f;
            int p0 = atomicExch(&head[n1 + a], s0);
            int p1 = atomicExch(&head[n1 + bl], s0 + 1);
            ((int4*)pairLL)[E_UB + f] = make_int4(p0, bl, p1, a);
        } else if (e < E_UB + E_UI + E_BI) {
            int g = e - E_UB - E_UI;
            int s = 2 * E_UB + 2 * E_UI + g;
            int p = atomicExch(&head[n1 + n2 + bi_b[g]], s);
            pairLL[s] = make_int2(p, bi_i[g]);
        }
    } else {
        int w = (((int)blockIdx.x - nblk_edges) * blockDim.x + threadIdx.x) >> 6;
        int lane = threadIdx.x & 63;
        if (w >= NT) return;
        const float* src = (w < NU) ? uf + (size_t)w * FD
                         : (w < NU + NB) ? bf + (size_t)(w - NU) * FD
                         : itf + (size_t)(w - NU - NB) * FD;
        float2 x = ((const float2*)src)[lane];
        float ss = wave_sum(x.x * x.x + x.y * x.y);
        float nrm = sqrtf(ss);
        float inv = 1.0f / fmaxf(nrm, 1e-12f);
        fini16[(size_t)w * FDH + lane] = packbf2(x.x * inv, x.y * inv);
        if (lane == 0) normf[w] = nrm;
    }
}

// ---------------- Pass B: chain length -> deg, dinv ----------------
__global__ void passB(const int* __restrict__ head, const int2* __restrict__ pairLL,
                      int NN, int n12, int* __restrict__ deg, float* __restrict__ dinv) {
    int r = blockIdx.x * blockDim.x + threadIdx.x;
    if (r > NN) return;
    if (r == NN) { deg[NN] = 0; return; }
    int c = 0;
    int s = head[r];
    while (s >= 0) { c++; s = pairLL[s].x; }
    deg[r] = c;
    if (r < n12) dinv[r] = 1.0f / (sqrtf((float)c) + EPSN);
}

// ---------------- conv_g8: g8[r] = fp8(fini[node(r)] * dinv[r] * norm[node(r)]) ------
__global__ void conv_g8(const uint* __restrict__ fini16, const float* __restrict__ normf,
                        const float* __restrict__ dinv,
                        int n1, int NU, int NB, int n12, u16* __restrict__ g8) {
    int w = (blockIdx.x * blockDim.x + threadIdx.x) >> 6;
    int lane = threadIdx.x & 63;
    if (w >= n12) return;
    int node = (w < n1) ? w : ((w - n1 < NU) ? (w - n1) : (w - n1 + NB));
    float sc = dinv[w] * normf[node];
    float2 f = unpackbf2(fini16[(size_t)node * FDH + lane]);
    g8[(size_t)w * FDH + lane] = packfp8(f.x * sc, f.y * sc);
}

// ---------------- exclusive scan ----------------
__global__ void scan_a(const int* __restrict__ in, int* __restrict__ out,
                       int* __restrict__ bsum, int nelem) {
    __shared__ int tsum[SCAN_TPB];
    int tid = threadIdx.x;
    int base = blockIdx.x * SCAN_ELEMS + tid * 4;
    int v0 = (base + 0 < nelem) ? in[base + 0] : 0;
    int v1 = (base + 1 < nelem) ? in[base + 1] : 0;
    int v2 = (base + 2 < nelem) ? in[base + 2] : 0;
    int v3 = (base + 3 < nelem) ? in[base + 3] : 0;
    int s = v0 + v1 + v2 + v3;
    tsum[tid] = s;
    __syncthreads();
    for (int off = 1; off < SCAN_TPB; off <<= 1) {
        int y = (tid >= off) ? tsum[tid - off] : 0;
        __syncthreads();
        tsum[tid] += y;
        __syncthreads();
    }
    int excl = tsum[tid] - s;
    if (tid == SCAN_TPB - 1) bsum[blockIdx.x] = tsum[SCAN_TPB - 1];
    if (base + 0 < nelem) out[base + 0] = excl;
    excl += v0;
    if (base + 1 < nelem) out[base + 1] = excl;
    excl += v1;
    if (base + 2 < nelem) out[base + 2] = excl;
    excl += v2;
    if (base + 3 < nelem) out[base + 3] = excl;
}

__global__ void scan_b(int* __restrict__ bsum, int nb) {   // nb <= 512
    __shared__ int sm[512];
    int tid = threadIdx.x;
    int v = (tid < nb) ? bsum[tid] : 0;
    sm[tid] = v;
    __syncthreads();
    for (int off = 1; off < 512; off <<= 1) {
        int y = (tid >= off) ? sm[tid - off] : 0;
        __syncthreads();
        sm[tid] += y;
        __syncthreads();
    }
    if (tid < nb) bsum[tid] = sm[tid] - v;
}

__global__ void scan_c(int* __restrict__ out, const int* __restrict__ bsum, int nelem) {
    int base = blockIdx.x * SCAN_ELEMS + threadIdx.x * 4;
    int add = bsum[blockIdx.x];
#pragma unroll
    for (int k = 0; k < 4; ++k)
        if (base + k < nelem) out[base + k] += add;
}

// ---------------- Pass C: flatten chains to CSR (cols stored as BYTE offsets) --------
// UB/UI rows: col<<7 (128-B fp8 rows). BI rows: col<<8 (256-B bf16 rows).
__global__ void passC(const int* __restrict__ head, const int2* __restrict__ pairLL,
                      const int* __restrict__ rowptr, const float* __restrict__ bi_vals,
                      int NN, int n12, int S1,
                      int* __restrict__ cols, float* __restrict__ wts) {
    int r = blockIdx.x * blockDim.x + threadIdx.x;
    if (r >= NN) return;
    int pos = rowptr[r];
    int s = head[r];
    if (r < n12) {
        while (s >= 0) { int2 p = pairLL[s]; cols[pos++] = p.y << 7; s = p.x; }
    } else {
        while (s >= 0) {
            int2 p = pairLL[s];
            cols[pos] = p.y << 8;
            wts[pos - S1] = bi_vals[s - S1];
            pos++; s = p.x;
        }
    }
}

// ======== half-wave fp8 gather core: lanes 0-31 = even edges, 32-63 = odd ========
// each lane loads u32 (4 fp8 = features 4q..4q+3); merge halves by shfl_xor(32)
#define GATHER_FP8(TAB)                                                          \
    float a0 = 0.f, a1 = 0.f, a2 = 0.f, a3 = 0.f;                                \
    {                                                                            \
        int j = s;                                                               \
        for (; j + 8 <= e; j += 8) {                                             \
            int o0 = cols[j + h], o1 = cols[j + 2 + h];                          \
            int o2 = cols[j + 4 + h], o3 = cols[j + 6 + h];                      \
            uint x0 = *(const uint*)(TAB + o0);                                  \
            uint x1 = *(const uint*)(TAB + o1);                                  \
            uint x2 = *(const uint*)(TAB + o2);                                  \
            uint x3 = *(const uint*)(TAB + o3);                                  \
            fx2 p0 = __builtin_amdgcn_cvt_pk_f32_fp8((int)x0, false);            \
            fx2 r0 = __builtin_amdgcn_cvt_pk_f32_fp8((int)x0, true);             \
            fx2 p1 = __builtin_amdgcn_cvt_pk_f32_fp8((int)x1, false);            \
            fx2 r1 = __builtin_amdgcn_cvt_pk_f32_fp8((int)x1, true);             \
            fx2 p2 = __builtin_amdgcn_cvt_pk_f32_fp8((int)x2, false);            \
            fx2 r2 = __builtin_amdgcn_cvt_pk_f32_fp8((int)x2, true);             \
            fx2 p3 = __builtin_amdgcn_cvt_pk_f32_fp8((int)x3, false);            \
            fx2 r3 = __builtin_amdgcn_cvt_pk_f32_fp8((int)x3, true);             \
            a0 += p0.x + p1.x + p2.x + p3.x;                                     \
            a1 += p0.y + p1.y + p2.y + p3.y;                                     \
            a2 += r0.x + r1.x + r2.x + r3.x;                                     \
            a3 += r0.y + r1.y + r2.y + r3.y;                                     \
        }                                                                        \
        for (; j + 2 <= e; j += 2) {                                             \
            int o = cols[j + h];                                                 \
            uint x = *(const uint*)(TAB + o);                                    \
            fx2 p = __builtin_amdgcn_cvt_pk_f32_fp8((int)x, false);              \
            fx2 r = __builtin_amdgcn_cvt_pk_f32_fp8((int)x, true);               \
            a0 += p.x; a1 += p.y; a2 += r.x; a3 += r.y;                          \
        }                                                                        \
        if (j < e && h == 0) {                                                   \
            int o = cols[j];                                                     \
            uint x = *(const uint*)(TAB + o);                                    \
            fx2 p = __builtin_amdgcn_cvt_pk_f32_fp8((int)x, false);              \
            fx2 r = __builtin_amdgcn_cvt_pk_f32_fp8((int)x, true);               \
            a0 += p.x; a1 += p.y; a2 += r.x; a3 += r.y;                          \
        }                                                                        \
    }                                                                            \
    a0 += __shfl_xor(a0, 32); a1 += __shfl_xor(a1, 32);                          \
    a2 += __shfl_xor(a2, 32); a3 += __shfl_xor(a3, 32);

// ---------------- Layer 1: pure gather of pre-scaled fp8 g8 ----------------
__global__ void spmm_L1(const int* __restrict__ rowptr, const int* __restrict__ cols,
                        const float* __restrict__ dinv, const float* __restrict__ normf,
                        const uint* __restrict__ fini16, const u16* __restrict__ g8,
                        uint* __restrict__ facc16, uint* __restrict__ fX8,
                        int n1, int NU, int NB, int n12) {
    int w = (blockIdx.x * blockDim.x + threadIdx.x) >> 6;
    int lane = threadIdx.x & 63;
    if (w >= n12) return;
    int h = lane >> 5, q = lane & 31;
    int s = rowptr[w], e = rowptr[w + 1];
    bool ui = (w >= n1);
    int node = ui ? ((w - n1 < NU) ? (w - n1) : (w - n1 + NB)) : w;
    float dr = dinv[w];
    const u8* tab = (const u8*)g8 + ((size_t)(ui ? n1 : 0) << 7) + (q << 2);
    GATHER_FP8(tab)
    uint2 iu = ((const uint2*)(fini16 + (size_t)node * FDH))[q];
    float2 i01 = unpackbf2(iu.x), i23 = unpackbf2(iu.y);
    float v0 = (dr * a0 + RCC * i01.x) * 0.5f;
    float v1 = (dr * a1 + RCC * i01.y) * 0.5f;
    float v2 = (dr * a2 + RCC * i23.x) * 0.5f;
    float v3 = (dr * a3 + RCC * i23.y) * 0.5f;
    float sq = v0 * v0 + v1 * v1 + v2 * v2 + v3 * v3;
#pragma unroll
    for (int off = 16; off > 0; off >>= 1) sq += __shfl_xor(sq, off);
    float inv = 1.0f / fmaxf(sqrtf(sq), 1e-12f);
    v0 *= inv; v1 *= inv; v2 *= inv; v3 *= inv;
    if (h == 0) {
        float nr = normf[node];
        uint2 fa;
        fa.x = packbf2(fmaf(i01.x, nr, v0), fmaf(i01.y, nr, v1));
        fa.y = packbf2(fmaf(i23.x, nr, v2), fmaf(i23.y, nr, v3));
        ((uint2*)(facc16 + (size_t)w * FDH))[q] = fa;
        int xu = __builtin_amdgcn_cvt_pk_fp8_f32(v0 * dr, v1 * dr, 0, false);
        xu = __builtin_amdgcn_cvt_pk_fp8_f32(v2 * dr, v3 * dr, xu, true);
        fX8[(size_t)w * 32 + q] = (uint)xu;
    }
}

// ---------------- Layer 2: pure gather from pre-scaled fp8 fX8 --------------
__global__ void spmm_L2(const int* __restrict__ rowptr, const int* __restrict__ cols,
                        const float* __restrict__ dinv, const uint* __restrict__ fini16,
                        const uint* __restrict__ facc16, const uint* __restrict__ fX8,
                        uint* __restrict__ items16, float* __restrict__ outp,
                        int n1, int NU, int NB, int n12) {
    int w = (blockIdx.x * blockDim.x + threadIdx.x) >> 6;
    int lane = threadIdx.x & 63;
    if (w >= n12) return;
    int h = lane >> 5, q = lane & 31;
    int s = rowptr[w], e = rowptr[w + 1];
    bool ui = (w >= n1);
    int node = ui ? ((w - n1 < NU) ? (w - n1) : (w - n1 + NB)) : w;
    float dr = dinv[w];
    const u8* tab = (const u8*)fX8 + ((size_t)(ui ? n1 : 0) << 7) + (q << 2);
    GATHER_FP8(tab)
    uint2 iu = ((const uint2*)(fini16 + (size_t)node * FDH))[q];
    float2 i01 = unpackbf2(iu.x), i23 = unpackbf2(iu.y);
    float v0 = (dr * a0 + RCC * i01.x) * (1.0f / 3.0f);
    float v1 = (dr * a1 + RCC * i01.y) * (1.0f / 3.0f);
    float v2 = (dr * a2 + RCC * i23.x) * (1.0f / 3.0f);
    float v3 = (dr * a3 + RCC * i23.y) * (1.0f / 3.0f);
    float sq = v0 * v0 + v1 * v1 + v2 * v2 + v3 * v3;
#pragma unroll
    for (int off = 16; off > 0; off >>= 1) sq += __shfl_xor(sq, off);
    float inv = 1.0f / fmaxf(sqrtf(sq), 1e-12f);
    v0 *= inv; v1 *= inv; v2 *= inv; v3 *= inv;
    uint2 au = ((const uint2*)(facc16 + (size_t)w * FDH))[q];
    float2 a01 = unpackbf2(au.x), a23 = unpackbf2(au.y);
    float n0 = a01.x + v0, o1v = a01.y + v1, n2v = a23.x + v2, n3 = a23.y + v3;
    if (h == 0) {
        if (!ui) {
            size_t dst = (w < NU) ? (size_t)(NU + w) : (size_t)(2 * NU + NB + (w - NU));
            ((float4*)(outp + dst * FD))[q] = make_float4(n0, o1v, n2v, n3);
        } else {
            int l = w - n1;
            if (l < NU) {
                ((float4*)(outp + (size_t)l * FD))[q] = make_float4(n0, o1v, n2v, n3);
            } else {
                uint2 it;
                it.x = packbf2(n0, o1v);
                it.y = packbf2(n2v, n3);
                ((uint2*)(items16 + (size_t)(l - NU) * FDH))[q] = it;
            }
        }
    }
}

// ---------------- BI gather from bf16 items (half-wave, uint2/lane) ----------------
__global__ void bi_gather(const int* __restrict__ rowptr, const int* __restrict__ cols,
                          const float* __restrict__ wts, int S1,
                          const uint* __restrict__ items16,
                          float* __restrict__ outb, int nb) {
    int w = (blockIdx.x * blockDim.x + threadIdx.x) >> 6;
    int lane = threadIdx.x & 63;
    if (w >= nb) return;
    int h = lane >> 5, q = lane & 31;
    int s = rowptr[w], e = rowptr[w + 1];
    const u8* tab = (const u8*)items16 + (q << 3);
    float a0 = 0.f, a1 = 0.f, a2 = 0.f, a3 = 0.f;
    int j = s;
    for (; j + 8 <= e; j += 8) {
        int o0 = cols[j + h], o1 = cols[j + 2 + h];
        int o2 = cols[j + 4 + h], o3 = cols[j + 6 + h];
        float w0 = wts[j + h - S1], w1 = wts[j + 2 + h - S1];
        float w2 = wts[j + 4 + h - S1], w3 = wts[j + 6 + h - S1];
        uint2 x0 = *(const uint2*)(tab + o0);
        uint2 x1 = *(const uint2*)(tab + o1);
        uint2 x2 = *(const uint2*)(tab + o2);
        uint2 x3 = *(const uint2*)(tab + o3);
        float2 f; 
        f = unpackbf2(x0.x); a0 = fmaf(w0, f.x, a0); a1 = fmaf(w0, f.y, a1);
        f = unpackbf2(x0.y); a2 = fmaf(w0, f.x, a2); a3 = fmaf(w0, f.y, a3);
        f = unpackbf2(x1.x); a0 = fmaf(w1, f.x, a0); a1 = fmaf(w1, f.y, a1);
        f = unpackbf2(x1.y); a2 = fmaf(w1, f.x, a2); a3 = fmaf(w1, f.y, a3);
        f = unpackbf2(x2.x); a0 = fmaf(w2, f.x, a0); a1 = fmaf(w2, f.y, a1);
        f = unpackbf2(x2.y); a2 = fmaf(w2, f.x, a2); a3 = fmaf(w2, f.y, a3);
        f = unpackbf2(x3.x); a0 = fmaf(w3, f.x, a0); a1 = fmaf(w3, f.y, a1);
        f = unpackbf2(x3.y); a2 = fmaf(w3, f.x, a2); a3 = fmaf(w3, f.y, a3);
    }
    for (; j + 2 <= e; j += 2) {
        int o = cols[j + h];
        float wt = wts[j + h - S1];
        uint2 x = *(const uint2*)(tab + o);
        float2 f;
        f = unpackbf2(x.x); a0 = fmaf(wt, f.x, a0); a1 = fmaf(wt, f.y, a1);
        f = unpackbf2(x.y); a2 = fmaf(wt, f.x, a2); a3 = fmaf(wt, f.y, a3);
    }
    if (j < e && h == 0) {
        int o = cols[j];
        float wt = wts[j - S1];
        uint2 x = *(const uint2*)(tab + o);
        float2 f;
        f = unpackbf2(x.x); a0 = fmaf(wt, f.x, a0); a1 = fmaf(wt, f.y, a1);
        f = unpackbf2(x.y); a2 = fmaf(wt, f.x, a2); a3 = fmaf(wt, f.y, a3);
    }
    a0 += __shfl_xor(a0, 32); a1 += __shfl_xor(a1, 32);
    a2 += __shfl_xor(a2, 32); a3 += __shfl_xor(a3, 32);
    if (h == 0)
        ((float4*)(outb + (size_t)w * FD))[q] = make_float4(a0, a1, a2, a3);
}

extern "C" void kernel_launch(void* const* d_in, const int* in_sizes, int n_in,
                              void* d_out, int out_size, void* d_ws, size_t ws_size,
                              hipStream_t stream) {
    const float* users   = (const float*)d_in[0];
    const float* bundles = (const float*)d_in[1];
    const float* items   = (const float*)d_in[2];
    const float* bi_vals = (const float*)d_in[3];
    const int* ub_u = (const int*)d_in[4];
    const int* ub_b = (const int*)d_in[5];
    const int* ui_u = (const int*)d_in[6];
    const int* ui_i = (const int*)d_in[7];
    const int* bi_b = (const int*)d_in[8];
    const int* bi_i = (const int*)d_in[9];

    const int NU = in_sizes[0] / FD;
    const int NB = in_sizes[1] / FD;
    const int NI = in_sizes[2] / FD;
    const int E_BI = in_sizes[3];
    const int E_UB = in_sizes[4];
    const int E_UI = in_sizes[6];
    float* out = (float*)d_out;

    const int n1 = NU + NB, n2 = NU + NI;
    const int n12 = n1 + n2;
    const int NT = NU + NB + NI;
    const int NN = n12 + NB;                        // total CSR rows
    const int S1 = 2 * E_UB + 2 * E_UI;             // first BI slot / BI rowptr base
    const int TOT = S1 + E_BI;                      // total CSR entries
    const int ETOT = E_UB + E_UI + E_BI;

    // ---- workspace layout ----
    uint* fini16   = (uint*)d_ws;                          // NT*FDH uints
    uint* facc16   = fini16 + (size_t)NT * FDH;            // n12*FDH uints
    uint* items16  = facc16 + (size_t)n12 * FDH;           // NI*FDH uints
    u16* g8        = (u16*)(items16 + (size_t)NI * FDH);   // n12*FDH u16
    uint* fX8      = (uint*)(g8 + (size_t)n12 * FDH);      // n12*32 uints
    float* normf   = (float*)(fX8 + (size_t)n12 * 32);     // NT
    float* dinv    = normf + NT;                           // n12
    float* wts     = dinv + n12;                           // E_BI
    int* deg       = (int*)(wts + E_BI);                   // NN+1
    int* rowptr    = deg + (NN + 1);                       // NN+1
    int* head      = rowptr + (NN + 1);                    // NN
    int* bsum      = head + NN;                            // 512
    int* cols      = bsum + 512;                           // TOT
    int2* pairLL   = (int2*)((((size_t)(cols + TOT)) + 15) & ~(size_t)15);  // TOT int2

    dim3 blk(256);
    auto rows_grid = [](int n) { return dim3((unsigned)((n + 3) / 4)); };
    auto thr_grid  = [](int n) { return dim3((unsigned)((n + 255) / 256)); };

    // ---- linked-list CSR build (one atomic pass) + fused feature prep ----
    hipMemsetAsync(head, 0xFF, (size_t)NN * 4, stream);    // head = -1
    int nblk_edges = (ETOT + 255) / 256;
    int nblk_prep  = (NT + 3) / 4;
    passA<<<dim3((unsigned)(nblk_edges + nblk_prep)), blk, 0, stream>>>(
        ub_u, ub_b, ui_u, ui_i, bi_b, bi_i, users, bundles, items,
        E_UB, E_UI, E_BI, NU, NB, n1, n2, NT, nblk_edges,
        head, pairLL, fini16, normf);
    passB<<<thr_grid(NN + 1), blk, 0, stream>>>(head, pairLL, NN, n12, deg, dinv);
    conv_g8<<<rows_grid(n12), blk, 0, stream>>>(fini16, normf, dinv, n1, NU, NB, n12, g8);
    {
        int nelem = NN + 1;
        int nblk = (nelem + SCAN_ELEMS - 1) / SCAN_ELEMS;
        scan_a<<<dim3((unsigned)nblk), dim3(SCAN_TPB), 0, stream>>>(deg, rowptr, bsum, nelem);
        scan_b<<<dim3(1), dim3(512), 0, stream>>>(bsum, nblk);
        scan_c<<<dim3((unsigned)nblk), dim3(SCAN_TPB), 0, stream>>>(rowptr, bsum, nelem);
    }
    passC<<<thr_grid(NN), blk, 0, stream>>>(head, pairLL, rowptr, bi_vals,
                                            NN, n12, S1, cols, wts);

    // ---- Layer 1 (UB + UI fused, half-wave fp8 gather) ----
    spmm_L1<<<rows_grid(n12), blk, 0, stream>>>(rowptr, cols, dinv, normf,
                                                fini16, g8, facc16, fX8, n1, NU, NB, n12);
    // ---- Layer 2 (UB + UI fused, half-wave fp8 gather) + writeout ----
    spmm_L2<<<rows_grid(n12), blk, 0, stream>>>(rowptr, cols, dinv, fini16,
                                                facc16, fX8, items16, out, n1, NU, NB, n12);
    // ---- BI aggregation ----
    bi_gather<<<rows_grid(NB), blk, 0, stream>>>(rowptr + n12, cols, wts, S1, items16,
        out + (size_t)2 * NU * FD, NB);
}

// Round 11
// 675.896 us; speedup vs baseline: 1.0722x; 1.0626x over previous
//
#include <hip/hip_runtime.h>

#define FD   128        // feature dim (floats)
#define FDH  64         // uints per bf16 row / u16s per fp8 row
#define EPSN 1e-8f
#define RCC  0.5f
#define SCAN_TPB 256
#define SCAN_ELEMS 1024

typedef unsigned int uint;
typedef unsigned short u16;
typedef unsigned char u8;
typedef float fx2 __attribute__((ext_vector_type(2)));

__device__ __forceinline__ float wave_sum(float x) {
#pragma unroll
    for (int off = 32; off > 0; off >>= 1) x += __shfl_xor(x, off);
    return x;
}

__device__ __forceinline__ uint packbf2(float a, float b) {
    uint ua = __float_as_uint(a); ua += 0x7fffu + ((ua >> 16) & 1u);
    uint ub = __float_as_uint(b); ub += 0x7fffu + ((ub >> 16) & 1u);
    return (ua >> 16) | (ub & 0xffff0000u);
}
__device__ __forceinline__ float2 unpackbf2(uint v) {
    return make_float2(__uint_as_float(v << 16), __uint_as_float(v & 0xffff0000u));
}
__device__ __forceinline__ u16 packfp8(float a, float b) { // 2x f32 -> 2x OCP e4m3
    return (u16)__builtin_amdgcn_cvt_pk_fp8_f32(a, b, 0, false);
}

// ---------------- Pass A: linked-list insert (1 atomicExch per insertion) + fused prep ----
__global__ void passA(const int* __restrict__ ub_u, const int* __restrict__ ub_b,
                      const int* __restrict__ ui_u, const int* __restrict__ ui_i,
                      const int* __restrict__ bi_b, const int* __restrict__ bi_i,
                      const float* __restrict__ uf, const float* __restrict__ bf,
                      const float* __restrict__ itf,
                      int E_UB, int E_UI, int E_BI, int NU, int NB, int n1, int n2, int NT,
                      int nblk_edges,
                      int* __restrict__ head, int2* __restrict__ pairLL,
                      uint* __restrict__ fini16, float* __restrict__ normf) {
    if ((int)blockIdx.x < nblk_edges) {
        int e = blockIdx.x * blockDim.x + threadIdx.x;
        if (e < E_UB) {
            int a = ub_u[e], b = ub_b[e] + NU;
            int s0 = 2 * e;
            int p0 = atomicExch(&head[a], s0);
            int p1 = atomicExch(&head[b], s0 + 1);
            ((int4*)pairLL)[e] = make_int4(p0, b, p1, a);
        } else if (e < E_UB + E_UI) {
            int f = e - E_UB;
            int a = ui_u[f], bl = ui_i[f] + NU;     // graph-local col ids
            int s0 = 2 * E_UB + 2 * f;
            int p0 = atomicExch(&head[n1 + a], s0);
            int p1 = atomicExch(&head[n1 + bl], s0 + 1);
            ((int4*)pairLL)[E_UB + f] = make_int4(p0, bl, p1, a);
        } else if (e < E_UB + E_UI + E_BI) {
            int g = e - E_UB - E_UI;
            int s = 2 * E_UB + 2 * E_UI + g;
            int p = atomicExch(&head[n1 + n2 + bi_b[g]], s);
            pairLL[s] = make_int2(p, bi_i[g]);
        }
    } else {
        int w = (((int)blockIdx.x - nblk_edges) * blockDim.x + threadIdx.x) >> 6;
        int lane = threadIdx.x & 63;
        if (w >= NT) return;
        const float* src = (w < NU) ? uf + (size_t)w * FD
                         : (w < NU + NB) ? bf + (size_t)(w - NU) * FD
                         : itf + (size_t)(w - NU - NB) * FD;
        float2 x = ((const float2*)src)[lane];
        float ss = wave_sum(x.x * x.x + x.y * x.y);
        float nrm = sqrtf(ss);
        float inv = 1.0f / fmaxf(nrm, 1e-12f);
        fini16[(size_t)w * FDH + lane] = packbf2(x.x * inv, x.y * inv);
        if (lane == 0) normf[w] = nrm;
    }
}

// ---------------- Pass B: chain length -> deg, dinv ----------------
__global__ void passB(const int* __restrict__ head, const int2* __restrict__ pairLL,
                      int NN, int n12, int* __restrict__ deg, float* __restrict__ dinv) {
    int r = blockIdx.x * blockDim.x + threadIdx.x;
    if (r > NN) return;
    if (r == NN) { deg[NN] = 0; return; }
    int c = 0;
    int s = head[r];
    while (s >= 0) { c++; s = pairLL[s].x; }
    deg[r] = c;
    if (r < n12) dinv[r] = 1.0f / (sqrtf((float)c) + EPSN);
}

// ---------------- conv_g8: g8[r] = fp8(fini[node(r)] * dinv[r] * norm[node(r)]) ------
__global__ void conv_g8(const uint* __restrict__ fini16, const float* __restrict__ normf,
                        const float* __restrict__ dinv,
                        int n1, int NU, int NB, int n12, u16* __restrict__ g8) {
    int w = (blockIdx.x * blockDim.x + threadIdx.x) >> 6;
    int lane = threadIdx.x & 63;
    if (w >= n12) return;
    int node = (w < n1) ? w : ((w - n1 < NU) ? (w - n1) : (w - n1 + NB));
    float sc = dinv[w] * normf[node];
    float2 f = unpackbf2(fini16[(size_t)node * FDH + lane]);
    g8[(size_t)w * FDH + lane] = packfp8(f.x * sc, f.y * sc);
}

// ---------------- exclusive scan ----------------
__global__ void scan_a(const int* __restrict__ in, int* __restrict__ out,
                       int* __restrict__ bsum, int nelem) {
    __shared__ int tsum[SCAN_TPB];
    int tid = threadIdx.x;
    int base = blockIdx.x * SCAN_ELEMS + tid * 4;
    int v0 = (base + 0 < nelem) ? in[base + 0] : 0;
    int v1 = (base + 1 < nelem) ? in[base + 1] : 0;
    int v2 = (base + 2 < nelem) ? in[base + 2] : 0;
    int v3 = (base + 3 < nelem) ? in[base + 3] : 0;
    int s = v0 + v1 + v2 + v3;
    tsum[tid] = s;
    __syncthreads();
    for (int off = 1; off < SCAN_TPB; off <<= 1) {
        int y = (tid >= off) ? tsum[tid - off] : 0;
        __syncthreads();
        tsum[tid] += y;
        __syncthreads();
    }
    int excl = tsum[tid] - s;
    if (tid == SCAN_TPB - 1) bsum[blockIdx.x] = tsum[SCAN_TPB - 1];
    if (base + 0 < nelem) out[base + 0] = excl;
    excl += v0;
    if (base + 1 < nelem) out[base + 1] = excl;
    excl += v1;
    if (base + 2 < nelem) out[base + 2] = excl;
    excl += v2;
    if (base + 3 < nelem) out[base + 3] = excl;
}

__global__ void scan_b(int* __restrict__ bsum, int nb) {   // nb <= 512
    __shared__ int sm[512];
    int tid = threadIdx.x;
    int v = (tid < nb) ? bsum[tid] : 0;
    sm[tid] = v;
    __syncthreads();
    for (int off = 1; off < 512; off <<= 1) {
        int y = (tid >= off) ? sm[tid - off] : 0;
        __syncthreads();
        sm[tid] += y;
        __syncthreads();
    }
    if (tid < nb) bsum[tid] = sm[tid] - v;
}

__global__ void scan_c(int* __restrict__ out, const int* __restrict__ bsum, int nelem) {
    int base = blockIdx.x * SCAN_ELEMS + threadIdx.x * 4;
    int add = bsum[blockIdx.x];
#pragma unroll
    for (int k = 0; k < 4; ++k)
        if (base + k < nelem) out[base + k] += add;
}

// ---------------- Pass C: flatten chains to CSR (cols stored as BYTE offsets) --------
// UB/UI rows: col<<7 (128-B fp8 rows). BI rows: col<<8 (256-B bf16 rows).
__global__ void passC(const int* __restrict__ head, const int2* __restrict__ pairLL,
                      const int* __restrict__ rowptr, const float* __restrict__ bi_vals,
                      int NN, int n12, int S1,
                      int* __restrict__ cols, float* __restrict__ wts) {
    int r = blockIdx.x * blockDim.x + threadIdx.x;
    if (r >= NN) return;
    int pos = rowptr[r];
    int s = head[r];
    if (r < n12) {
        while (s >= 0) { int2 p = pairLL[s]; cols[pos++] = p.y << 7; s = p.x; }
    } else {
        while (s >= 0) {
            int2 p = pairLL[s];
            cols[pos] = p.y << 8;
            wts[pos - S1] = bi_vals[s - S1];
            pos++; s = p.x;
        }
    }
}

// ======== half-wave fp8 gather core, register-broadcast offsets ========
// One coalesced load fetches cols[cs..cs+cnt) into lanes; per-edge offsets come
// from __shfl broadcasts (no memory loads in the inner loop). Lanes 0-31 handle
// even edges, 32-63 odd edges; each lane loads u32 = 4 fp8 features.
#define GATHER_FP8(TAB)                                                          \
    float a0 = 0.f, a1 = 0.f, a2 = 0.f, a3 = 0.f;                                \
    for (int cs = s; cs < e; cs += 64) {                                         \
        int cnt = e - cs; if (cnt > 64) cnt = 64;                                \
        int colv = (lane < cnt) ? cols[cs + lane] : 0;                           \
        int p = 0;                                                               \
        for (; 2 * p + 8 <= cnt; p += 4) {                                       \
            int o0 = __shfl(colv, 2 * p + h);                                    \
            int o1 = __shfl(colv, 2 * p + 2 + h);                                \
            int o2 = __shfl(colv, 2 * p + 4 + h);                                \
            int o3 = __shfl(colv, 2 * p + 6 + h);                                \
            uint x0 = *(const uint*)(TAB + o0);                                  \
            uint x1 = *(const uint*)(TAB + o1);                                  \
            uint x2 = *(const uint*)(TAB + o2);                                  \
            uint x3 = *(const uint*)(TAB + o3);                                  \
            fx2 p0 = __builtin_amdgcn_cvt_pk_f32_fp8((int)x0, false);            \
            fx2 r0 = __builtin_amdgcn_cvt_pk_f32_fp8((int)x0, true);             \
            fx2 p1 = __builtin_amdgcn_cvt_pk_f32_fp8((int)x1, false);            \
            fx2 r1 = __builtin_amdgcn_cvt_pk_f32_fp8((int)x1, true);             \
            fx2 p2 = __builtin_amdgcn_cvt_pk_f32_fp8((int)x2, false);            \
            fx2 r2 = __builtin_amdgcn_cvt_pk_f32_fp8((int)x2, true);             \
            fx2 p3 = __builtin_amdgcn_cvt_pk_f32_fp8((int)x3, false);            \
            fx2 r3 = __builtin_amdgcn_cvt_pk_f32_fp8((int)x3, true);             \
            a0 += p0.x + p1.x + p2.x + p3.x;                                     \
            a1 += p0.y + p1.y + p2.y + p3.y;                                     \
            a2 += r0.x + r1.x + r2.x + r3.x;                                     \
            a3 += r0.y + r1.y + r2.y + r3.y;                                     \
        }                                                                        \
        for (; 2 * p + 2 <= cnt; ++p) {                                          \
            int o = __shfl(colv, 2 * p + h);                                     \
            uint x = *(const uint*)(TAB + o);                                    \
            fx2 pp = __builtin_amdgcn_cvt_pk_f32_fp8((int)x, false);             \
            fx2 rr = __builtin_amdgcn_cvt_pk_f32_fp8((int)x, true);              \
            a0 += pp.x; a1 += pp.y; a2 += rr.x; a3 += rr.y;                      \
        }                                                                        \
        if (2 * p < cnt) {                                                       \
            int o = __shfl(colv, 2 * p);                                         \
            if (h == 0) {                                                        \
                uint x = *(const uint*)(TAB + o);                                \
                fx2 pp = __builtin_amdgcn_cvt_pk_f32_fp8((int)x, false);         \
                fx2 rr = __builtin_amdgcn_cvt_pk_f32_fp8((int)x, true);          \
                a0 += pp.x; a1 += pp.y; a2 += rr.x; a3 += rr.y;                  \
            }                                                                    \
        }                                                                        \
    }                                                                            \
    a0 += __shfl_xor(a0, 32); a1 += __shfl_xor(a1, 32);                          \
    a2 += __shfl_xor(a2, 32); a3 += __shfl_xor(a3, 32);

// ---------------- Layer 1: pure gather of pre-scaled fp8 g8 ----------------
__global__ void spmm_L1(const int* __restrict__ rowptr, const int* __restrict__ cols,
                        const float* __restrict__ dinv, const float* __restrict__ normf,
                        const uint* __restrict__ fini16, const u16* __restrict__ g8,
                        uint* __restrict__ facc16, uint* __restrict__ fX8,
                        int n1, int NU, int NB, int n12) {
    int w = (blockIdx.x * blockDim.x + threadIdx.x) >> 6;
    int lane = threadIdx.x & 63;
    if (w >= n12) return;
    int h = lane >> 5, q = lane & 31;
    int s = rowptr[w], e = rowptr[w + 1];
    bool ui = (w >= n1);
    int node = ui ? ((w - n1 < NU) ? (w - n1) : (w - n1 + NB)) : w;
    float dr = dinv[w];
    // hoisted epilogue loads (overlap with gather latency)
    uint2 iu = ((const uint2*)(fini16 + (size_t)node * FDH))[q];
    float nr = normf[node];
    const u8* tab = (const u8*)g8 + ((size_t)(ui ? n1 : 0) << 7) + (q << 2);
    GATHER_FP8(tab)
    float2 i01 = unpackbf2(iu.x), i23 = unpackbf2(iu.y);
    float v0 = (dr * a0 + RCC * i01.x) * 0.5f;
    float v1 = (dr * a1 + RCC * i01.y) * 0.5f;
    float v2 = (dr * a2 + RCC * i23.x) * 0.5f;
    float v3 = (dr * a3 + RCC * i23.y) * 0.5f;
    float sq = v0 * v0 + v1 * v1 + v2 * v2 + v3 * v3;
#pragma unroll
    for (int off = 16; off > 0; off >>= 1) sq += __shfl_xor(sq, off);
    float inv = 1.0f / fmaxf(sqrtf(sq), 1e-12f);
    v0 *= inv; v1 *= inv; v2 *= inv; v3 *= inv;
    if (h == 0) {
        uint2 fa;
        fa.x = packbf2(fmaf(i01.x, nr, v0), fmaf(i01.y, nr, v1));
        fa.y = packbf2(fmaf(i23.x, nr, v2), fmaf(i23.y, nr, v3));
        ((uint2*)(facc16 + (size_t)w * FDH))[q] = fa;
        int xu = __builtin_amdgcn_cvt_pk_fp8_f32(v0 * dr, v1 * dr, 0, false);
        xu = __builtin_amdgcn_cvt_pk_fp8_f32(v2 * dr, v3 * dr, xu, true);
        fX8[(size_t)w * 32 + q] = (uint)xu;
    }
}

// ---------------- Layer 2: pure gather from pre-scaled fp8 fX8 --------------
__global__ void spmm_L2(const int* __restrict__ rowptr, const int* __restrict__ cols,
                        const float* __restrict__ dinv, const uint* __restrict__ fini16,
                        const uint* __restrict__ facc16, const uint* __restrict__ fX8,
                        uint* __restrict__ items16, float* __restrict__ outp,
                        int n1, int NU, int NB, int n12) {
    int w = (blockIdx.x * blockDim.x + threadIdx.x) >> 6;
    int lane = threadIdx.x & 63;
    if (w >= n12) return;
    int h = lane >> 5, q = lane & 31;
    int s = rowptr[w], e = rowptr[w + 1];
    bool ui = (w >= n1);
    int node = ui ? ((w - n1 < NU) ? (w - n1) : (w - n1 + NB)) : w;
    float dr = dinv[w];
    // hoisted epilogue loads
    uint2 iu = ((const uint2*)(fini16 + (size_t)node * FDH))[q];
    uint2 au = ((const uint2*)(facc16 + (size_t)w * FDH))[q];
    const u8* tab = (const u8*)fX8 + ((size_t)(ui ? n1 : 0) << 7) + (q << 2);
    GATHER_FP8(tab)
    float2 i01 = unpackbf2(iu.x), i23 = unpackbf2(iu.y);
    float v0 = (dr * a0 + RCC * i01.x) * (1.0f / 3.0f);
    float v1 = (dr * a1 + RCC * i01.y) * (1.0f / 3.0f);
    float v2 = (dr * a2 + RCC * i23.x) * (1.0f / 3.0f);
    float v3 = (dr * a3 + RCC * i23.y) * (1.0f / 3.0f);
    float sq = v0 * v0 + v1 * v1 + v2 * v2 + v3 * v3;
#pragma unroll
    for (int off = 16; off > 0; off >>= 1) sq += __shfl_xor(sq, off);
    float inv = 1.0f / fmaxf(sqrtf(sq), 1e-12f);
    v0 *= inv; v1 *= inv; v2 *= inv; v3 *= inv;
    float2 a01 = unpackbf2(au.x), a23 = unpackbf2(au.y);
    float n0 = a01.x + v0, o1v = a01.y + v1, n2v = a23.x + v2, n3 = a23.y + v3;
    if (h == 0) {
        if (!ui) {
            size_t dst = (w < NU) ? (size_t)(NU + w) : (size_t)(2 * NU + NB + (w - NU));
            ((float4*)(outp + dst * FD))[q] = make_float4(n0, o1v, n2v, n3);
        } else {
            int l = w - n1;
            if (l < NU) {
                ((float4*)(outp + (size_t)l * FD))[q] = make_float4(n0, o1v, n2v, n3);
            } else {
                uint2 it;
                it.x = packbf2(n0, o1v);
                it.y = packbf2(n2v, n3);
                ((uint2*)(items16 + (size_t)(l - NU) * FDH))[q] = it;
            }
        }
    }
}

// ---------------- BI gather from bf16 items (half-wave, register-broadcast) ----------
__global__ void bi_gather(const int* __restrict__ rowptr, const int* __restrict__ cols,
                          const float* __restrict__ wts, int S1,
                          const uint* __restrict__ items16,
                          float* __restrict__ outb, int nb) {
    int w = (blockIdx.x * blockDim.x + threadIdx.x) >> 6;
    int lane = threadIdx.x & 63;
    if (w >= nb) return;
    int h = lane >> 5, q = lane & 31;
    int s = rowptr[w], e = rowptr[w + 1];
    const u8* tab = (const u8*)items16 + (q << 3);
    float a0 = 0.f, a1 = 0.f, a2 = 0.f, a3 = 0.f;
    for (int cs = s; cs < e; cs += 64) {
        int cnt = e - cs; if (cnt > 64) cnt = 64;
        int colv = (lane < cnt) ? cols[cs + lane] : 0;
        float wtv = (lane < cnt) ? wts[cs + lane - S1] : 0.0f;
        int p = 0;
        for (; 2 * p + 8 <= cnt; p += 4) {
            int o0 = __shfl(colv, 2 * p + h);
            int o1 = __shfl(colv, 2 * p + 2 + h);
            int o2 = __shfl(colv, 2 * p + 4 + h);
            int o3 = __shfl(colv, 2 * p + 6 + h);
            float w0 = __shfl(wtv, 2 * p + h);
            float w1 = __shfl(wtv, 2 * p + 2 + h);
            float w2 = __shfl(wtv, 2 * p + 4 + h);
            float w3 = __shfl(wtv, 2 * p + 6 + h);
            uint2 x0 = *(const uint2*)(tab + o0);
            uint2 x1 = *(const uint2*)(tab + o1);
            uint2 x2 = *(const uint2*)(tab + o2);
            uint2 x3 = *(const uint2*)(tab + o3);
            float2 f;
            f = unpackbf2(x0.x); a0 = fmaf(w0, f.x, a0); a1 = fmaf(w0, f.y, a1);
            f = unpackbf2(x0.y); a2 = fmaf(w0, f.x, a2); a3 = fmaf(w0, f.y, a3);
            f = unpackbf2(x1.x); a0 = fmaf(w1, f.x, a0); a1 = fmaf(w1, f.y, a1);
            f = unpackbf2(x1.y); a2 = fmaf(w1, f.x, a2); a3 = fmaf(w1, f.y, a3);
            f = unpackbf2(x2.x); a0 = fmaf(w2, f.x, a0); a1 = fmaf(w2, f.y, a1);
            f = unpackbf2(x2.y); a2 = fmaf(w2, f.x, a2); a3 = fmaf(w2, f.y, a3);
            f = unpackbf2(x3.x); a0 = fmaf(w3, f.x, a0); a1 = fmaf(w3, f.y, a1);
            f = unpackbf2(x3.y); a2 = fmaf(w3, f.x, a2); a3 = fmaf(w3, f.y, a3);
        }
        for (; 2 * p + 2 <= cnt; ++p) {
            int o = __shfl(colv, 2 * p + h);
            float wt = __shfl(wtv, 2 * p + h);
            uint2 x = *(const uint2*)(tab + o);
            float2 f;
            f = unpackbf2(x.x); a0 = fmaf(wt, f.x, a0); a1 = fmaf(wt, f.y, a1);
            f = unpackbf2(x.y); a2 = fmaf(wt, f.x, a2); a3 = fmaf(wt, f.y, a3);
        }
        if (2 * p < cnt) {
            int o = __shfl(colv, 2 * p);
            float wt = __shfl(wtv, 2 * p);
            if (h == 0) {
                uint2 x = *(const uint2*)(tab + o);
                float2 f;
                f = unpackbf2(x.x); a0 = fmaf(wt, f.x, a0); a1 = fmaf(wt, f.y, a1);
                f = unpackbf2(x.y); a2 = fmaf(wt, f.x, a2); a3 = fmaf(wt, f.y, a3);
            }
        }
    }
    a0 += __shfl_xor(a0, 32); a1 += __shfl_xor(a1, 32);
    a2 += __shfl_xor(a2, 32); a3 += __shfl_xor(a3, 32);
    if (h == 0)
        ((float4*)(outb + (size_t)w * FD))[q] = make_float4(a0, a1, a2, a3);
}

extern "C" void kernel_launch(void* const* d_in, const int* in_sizes, int n_in,
                              void* d_out, int out_size, void* d_ws, size_t ws_size,
                              hipStream_t stream) {
    const float* users   = (const float*)d_in[0];
    const float* bundles = (const float*)d_in[1];
    const float* items   = (const float*)d_in[2];
    const float* bi_vals = (const float*)d_in[3];
    const int* ub_u = (const int*)d_in[4];
    const int* ub_b = (const int*)d_in[5];
    const int* ui_u = (const int*)d_in[6];
    const int* ui_i = (const int*)d_in[7];
    const int* bi_b = (const int*)d_in[8];
    const int* bi_i = (const int*)d_in[9];

    const int NU = in_sizes[0] / FD;
    const int NB = in_sizes[1] / FD;
    const int NI = in_sizes[2] / FD;
    const int E_BI = in_sizes[3];
    const int E_UB = in_sizes[4];
    const int E_UI = in_sizes[6];
    float* out = (float*)d_out;

    const int n1 = NU + NB, n2 = NU + NI;
    const int n12 = n1 + n2;
    const int NT = NU + NB + NI;
    const int NN = n12 + NB;                        // total CSR rows
    const int S1 = 2 * E_UB + 2 * E_UI;             // first BI slot / BI rowptr base
    const int TOT = S1 + E_BI;                      // total CSR entries
    const int ETOT = E_UB + E_UI + E_BI;

    // ---- workspace layout ----
    uint* fini16   = (uint*)d_ws;                          // NT*FDH uints
    uint* facc16   = fini16 + (size_t)NT * FDH;            // n12*FDH uints
    uint* items16  = facc16 + (size_t)n12 * FDH;           // NI*FDH uints
    u16* g8        = (u16*)(items16 + (size_t)NI * FDH);   // n12*FDH u16
    uint* fX8      = (uint*)(g8 + (size_t)n12 * FDH);      // n12*32 uints
    float* normf   = (float*)(fX8 + (size_t)n12 * 32);     // NT
    float* dinv    = normf + NT;                           // n12
    float* wts     = dinv + n12;                           // E_BI
    int* deg       = (int*)(wts + E_BI);                   // NN+1
    int* rowptr    = deg + (NN + 1);                       // NN+1
    int* head      = rowptr + (NN + 1);                    // NN
    int* bsum      = head + NN;                            // 512
    int* cols      = bsum + 512;                           // TOT
    int2* pairLL   = (int2*)((((size_t)(cols + TOT)) + 15) & ~(size_t)15);  // TOT int2

    dim3 blk(256);
    auto rows_grid = [](int n) { return dim3((unsigned)((n + 3) / 4)); };
    auto thr_grid  = [](int n) { return dim3((unsigned)((n + 255) / 256)); };

    // ---- linked-list CSR build (one atomic pass) + fused feature prep ----
    hipMemsetAsync(head, 0xFF, (size_t)NN * 4, stream);    // head = -1
    int nblk_edges = (ETOT + 255) / 256;
    int nblk_prep  = (NT + 3) / 4;
    passA<<<dim3((unsigned)(nblk_edges + nblk_prep)), blk, 0, stream>>>(
        ub_u, ub_b, ui_u, ui_i, bi_b, bi_i, users, bundles, items,
        E_UB, E_UI, E_BI, NU, NB, n1, n2, NT, nblk_edges,
        head, pairLL, fini16, normf);
    passB<<<thr_grid(NN + 1), blk, 0, stream>>>(head, pairLL, NN, n12, deg, dinv);
    conv_g8<<<rows_grid(n12), blk, 0, stream>>>(fini16, normf, dinv, n1, NU, NB, n12, g8);
    {
        int nelem = NN + 1;
        int nblk = (nelem + SCAN_ELEMS - 1) / SCAN_ELEMS;
        scan_a<<<dim3((unsigned)nblk), dim3(SCAN_TPB), 0, stream>>>(deg, rowptr, bsum, nelem);
        scan_b<<<dim3(1), dim3(512), 0, stream>>>(bsum, nblk);
        scan_c<<<dim3((unsigned)nblk), dim3(SCAN_TPB), 0, stream>>>(rowptr, bsum, nelem);
    }
    passC<<<thr_grid(NN), blk, 0, stream>>>(head, pairLL, rowptr, bi_vals,
                                            NN, n12, S1, cols, wts);

    // ---- Layer 1 (UB + UI fused, register-broadcast fp8 gather) ----
    spmm_L1<<<rows_grid(n12), blk, 0, stream>>>(rowptr, cols, dinv, normf,
                                                fini16, g8, facc16, fX8, n1, NU, NB, n12);
    // ---- Layer 2 (UB + UI fused, register-broadcast fp8 gather) + writeout ----
    spmm_L2<<<rows_grid(n12), blk, 0, stream>>>(rowptr, cols, dinv, fini16,
                                                facc16, fX8, items16, out, n1, NU, NB, n12);
    // ---- BI aggregation ----
    bi_gather<<<rows_grid(NB), blk, 0, stream>>>(rowptr + n12, cols, wts, S1, items16,
        out + (size_t)2 * NU * FD, NB);
}

// Round 12
// 601.777 us; speedup vs baseline: 1.2042x; 1.1232x over previous
//
#include <hip/hip_runtime.h>

#define FD   128        // feature dim (floats)
#define FDH  64         // uints per bf16 row / u16s per fp8 row
#define EPSN 1e-8f
#define RCC  0.5f
#define SCAN_TPB 256
#define SCAN_ELEMS 1024

typedef unsigned int uint;
typedef unsigned short u16;
typedef unsigned char u8;
typedef float fx2 __attribute__((ext_vector_type(2)));

__device__ __forceinline__ float wave_sum(float x) {
#pragma unroll
    for (int off = 32; off > 0; off >>= 1) x += __shfl_xor(x, off);
    return x;
}

__device__ __forceinline__ uint packbf2(float a, float b) {
    uint ua = __float_as_uint(a); ua += 0x7fffu + ((ua >> 16) & 1u);
    uint ub = __float_as_uint(b); ub += 0x7fffu + ((ub >> 16) & 1u);
    return (ua >> 16) | (ub & 0xffff0000u);
}
__device__ __forceinline__ float2 unpackbf2(uint v) {
    return make_float2(__uint_as_float(v << 16), __uint_as_float(v & 0xffff0000u));
}
__device__ __forceinline__ u16 packfp8(float a, float b) { // 2x f32 -> 2x OCP e4m3
    return (u16)__builtin_amdgcn_cvt_pk_fp8_f32(a, b, 0, false);
}

// ---------------- Pass A: linked-list insert (1 atomicExch per insertion) + fused prep ----
__global__ void passA(const int* __restrict__ ub_u, const int* __restrict__ ub_b,
                      const int* __restrict__ ui_u, const int* __restrict__ ui_i,
                      const int* __restrict__ bi_b, const int* __restrict__ bi_i,
                      const float* __restrict__ uf, const float* __restrict__ bf,
                      const float* __restrict__ itf,
                      int E_UB, int E_UI, int E_BI, int NU, int NB, int n1, int n2, int NT,
                      int nblk_edges,
                      int* __restrict__ head, int2* __restrict__ pairLL,
                      uint* __restrict__ fini16, float* __restrict__ normf) {
    if ((int)blockIdx.x < nblk_edges) {
        int e = blockIdx.x * blockDim.x + threadIdx.x;
        if (e < E_UB) {
            int a = ub_u[e], b = ub_b[e] + NU;
            int s0 = 2 * e;
            int p0 = atomicExch(&head[a], s0);
            int p1 = atomicExch(&head[b], s0 + 1);
            ((int4*)pairLL)[e] = make_int4(p0, b, p1, a);
        } else if (e < E_UB + E_UI) {
            int f = e - E_UB;
            int a = ui_u[f], bl = ui_i[f] + NU;     // graph-local col ids
            int s0 = 2 * E_UB + 2 * f;
            int p0 = atomicExch(&head[n1 + a], s0);
            int p1 = atomicExch(&head[n1 + bl], s0 + 1);
            ((int4*)pairLL)[E_UB + f] = make_int4(p0, bl, p1, a);
        } else if (e < E_UB + E_UI + E_BI) {
            int g = e - E_UB - E_UI;
            int s = 2 * E_UB + 2 * E_UI + g;
            int p = atomicExch(&head[n1 + n2 + bi_b[g]], s);
            pairLL[s] = make_int2(p, bi_i[g]);
        }
    } else {
        int w = (((int)blockIdx.x - nblk_edges) * blockDim.x + threadIdx.x) >> 6;
        int lane = threadIdx.x & 63;
        if (w >= NT) return;
        const float* src = (w < NU) ? uf + (size_t)w * FD
                         : (w < NU + NB) ? bf + (size_t)(w - NU) * FD
                         : itf + (size_t)(w - NU - NB) * FD;
        float2 x = ((const float2*)src)[lane];
        float ss = wave_sum(x.x * x.x + x.y * x.y);
        float nrm = sqrtf(ss);
        float inv = 1.0f / fmaxf(nrm, 1e-12f);
        fini16[(size_t)w * FDH + lane] = packbf2(x.x * inv, x.y * inv);
        if (lane == 0) normf[w] = nrm;
    }
}

// ---------------- Pass B: chain length -> deg, dinv ----------------
__global__ void passB(const int* __restrict__ head, const int2* __restrict__ pairLL,
                      int NN, int n12, int* __restrict__ deg, float* __restrict__ dinv) {
    int r = blockIdx.x * blockDim.x + threadIdx.x;
    if (r > NN) return;
    if (r == NN) { deg[NN] = 0; return; }
    int c = 0;
    int s = head[r];
    while (s >= 0) { c++; s = pairLL[s].x; }
    deg[r] = c;
    if (r < n12) dinv[r] = 1.0f / (sqrtf((float)c) + EPSN);
}

// ---------------- exclusive scan ----------------
__global__ void scan_a(const int* __restrict__ in, int* __restrict__ out,
                       int* __restrict__ bsum, int nelem) {
    __shared__ int tsum[SCAN_TPB];
    int tid = threadIdx.x;
    int base = blockIdx.x * SCAN_ELEMS + tid * 4;
    int v0 = (base + 0 < nelem) ? in[base + 0] : 0;
    int v1 = (base + 1 < nelem) ? in[base + 1] : 0;
    int v2 = (base + 2 < nelem) ? in[base + 2] : 0;
    int v3 = (base + 3 < nelem) ? in[base + 3] : 0;
    int s = v0 + v1 + v2 + v3;
    tsum[tid] = s;
    __syncthreads();
    for (int off = 1; off < SCAN_TPB; off <<= 1) {
        int y = (tid >= off) ? tsum[tid - off] : 0;
        __syncthreads();
        tsum[tid] += y;
        __syncthreads();
    }
    int excl = tsum[tid] - s;
    if (tid == SCAN_TPB - 1) bsum[blockIdx.x] = tsum[SCAN_TPB - 1];
    if (base + 0 < nelem) out[base + 0] = excl;
    excl += v0;
    if (base + 1 < nelem) out[base + 1] = excl;
    excl += v1;
    if (base + 2 < nelem) out[base + 2] = excl;
    excl += v2;
    if (base + 3 < nelem) out[base + 3] = excl;
}

__global__ void scan_b(int* __restrict__ bsum, int nb) {   // nb <= 512
    __shared__ int sm[512];
    int tid = threadIdx.x;
    int v = (tid < nb) ? bsum[tid] : 0;
    sm[tid] = v;
    __syncthreads();
    for (int off = 1; off < 512; off <<= 1) {
        int y = (tid >= off) ? sm[tid - off] : 0;
        __syncthreads();
        sm[tid] += y;
        __syncthreads();
    }
    if (tid < nb) bsum[tid] = sm[tid] - v;
}

__global__ void scan_c(int* __restrict__ out, const int* __restrict__ bsum, int nelem) {
    int base = blockIdx.x * SCAN_ELEMS + threadIdx.x * 4;
    int add = bsum[blockIdx.x];
#pragma unroll
    for (int k = 0; k < 4; ++k)
        if (base + k < nelem) out[base + k] += add;
}

// ---------------- Pass C (+ fused conv_g8): flatten chains to CSR ----------------
// UB/UI rows: cols[pos] = col<<7 (128-B fp8 rows). BI rows: bi2[pos-S1] = {col<<8, wt}.
// conv part: g8[r] = fp8(fini[node(r)] * dinv[r] * norm[node(r)])
__global__ void passC_conv(const int* __restrict__ head, const int2* __restrict__ pairLL,
                           const int* __restrict__ rowptr, const float* __restrict__ bi_vals,
                           int NN, int n12, int S1,
                           int* __restrict__ cols, int2* __restrict__ bi2,
                           const uint* __restrict__ fini16, const float* __restrict__ normf,
                           const float* __restrict__ dinv,
                           int n1, int NU, int NB, u16* __restrict__ g8, int nblkC) {
    if ((int)blockIdx.x < nblkC) {
        int r = blockIdx.x * blockDim.x + threadIdx.x;
        if (r >= NN) return;
        int pos = rowptr[r];
        int s = head[r];
        if (r < n12) {
            while (s >= 0) { int2 p = pairLL[s]; cols[pos++] = p.y << 7; s = p.x; }
        } else {
            while (s >= 0) {
                int2 p = pairLL[s];
                bi2[pos - S1] = make_int2(p.y << 8, __float_as_int(bi_vals[s - S1]));
                pos++; s = p.x;
            }
        }
    } else {
        int w = (((int)blockIdx.x - nblkC) * blockDim.x + threadIdx.x) >> 6;
        int lane = threadIdx.x & 63;
        if (w >= n12) return;
        int node = (w < n1) ? w : ((w - n1 < NU) ? (w - n1) : (w - n1 + NB));
        float sc = dinv[w] * normf[node];
        float2 f = unpackbf2(fini16[(size_t)node * FDH + lane]);
        g8[(size_t)w * FDH + lane] = packfp8(f.x * sc, f.y * sc);
    }
}

// ======== 2-rows-per-wave fp8 gather core ========
// half-wave hw (32 lanes) owns one row; 16-lane groups (sub) process 2 edges at
// once; each lane loads uint2 = 8 fp8 features (features 8t..8t+7).
#define ACC8(XU)  {                                                              \
    fx2 _pa = __builtin_amdgcn_cvt_pk_f32_fp8((int)(XU).x, false);               \
    fx2 _pb = __builtin_amdgcn_cvt_pk_f32_fp8((int)(XU).x, true);                \
    fx2 _pc = __builtin_amdgcn_cvt_pk_f32_fp8((int)(XU).y, false);               \
    fx2 _pd = __builtin_amdgcn_cvt_pk_f32_fp8((int)(XU).y, true);                \
    a0 += _pa.x; a1 += _pa.y; a2 += _pb.x; a3 += _pb.y;                          \
    a4 += _pc.x; a5 += _pc.y; a6 += _pd.x; a7 += _pd.y; }

#define GATHER8(TAB)                                                             \
    float a0=0.f,a1=0.f,a2=0.f,a3=0.f,a4=0.f,a5=0.f,a6=0.f,a7=0.f;               \
    {                                                                            \
      int base = lane & 32;                                                      \
      for (int cs = s; cs < e; cs += 32) {                                       \
        int cnt = e - cs; if (cnt > 32) cnt = 32;                                \
        int colv = (l31 < cnt) ? cols[cs + l31] : 0;                             \
        int p = 0;                                                               \
        for (; 2 * p + 8 <= cnt; p += 4) {                                       \
            int o0 = __shfl(colv, base + 2 * p + sub);                           \
            int o1 = __shfl(colv, base + 2 * p + 2 + sub);                       \
            int o2 = __shfl(colv, base + 2 * p + 4 + sub);                       \
            int o3 = __shfl(colv, base + 2 * p + 6 + sub);                       \
            uint2 x0 = *(const uint2*)(TAB + o0);                                \
            uint2 x1 = *(const uint2*)(TAB + o1);                                \
            uint2 x2 = *(const uint2*)(TAB + o2);                                \
            uint2 x3 = *(const uint2*)(TAB + o3);                                \
            ACC8(x0) ACC8(x1) ACC8(x2) ACC8(x3)                                  \
        }                                                                        \
        for (; 2 * p + 2 <= cnt; ++p) {                                          \
            int o = __shfl(colv, base + 2 * p + sub);                            \
            uint2 x = *(const uint2*)(TAB + o);                                  \
            ACC8(x)                                                              \
        }                                                                        \
        if (2 * p < cnt) {                                                       \
            int o = __shfl(colv, base + 2 * p);                                  \
            if (sub == 0) { uint2 x = *(const uint2*)(TAB + o); ACC8(x) }        \
        }                                                                        \
      }                                                                          \
    }                                                                            \
    a0 += __shfl_xor(a0, 16); a1 += __shfl_xor(a1, 16);                          \
    a2 += __shfl_xor(a2, 16); a3 += __shfl_xor(a3, 16);                          \
    a4 += __shfl_xor(a4, 16); a5 += __shfl_xor(a5, 16);                          \
    a6 += __shfl_xor(a6, 16); a7 += __shfl_xor(a7, 16);

// ---------------- Layer 1: pure gather of pre-scaled fp8 g8 (2 rows/wave) -------------
__global__ void spmm_L1(const int* __restrict__ rowptr, const int* __restrict__ cols,
                        const float* __restrict__ dinv, const float* __restrict__ normf,
                        const uint* __restrict__ fini16, const u16* __restrict__ g8,
                        uint* __restrict__ facc16, uint* __restrict__ fX8,
                        int n1, int NU, int NB, int n12) {
    int wv = (blockIdx.x * blockDim.x + threadIdx.x) >> 6;
    int lane = threadIdx.x & 63;
    int hw = lane >> 5, l31 = lane & 31, sub = (lane >> 4) & 1, t = lane & 15;
    int r = 2 * wv + hw;
    if (r >= n12) return;
    int s = rowptr[r], e = rowptr[r + 1];
    bool ui = (r >= n1);
    int node = ui ? ((r - n1 < NU) ? (r - n1) : (r - n1 + NB)) : r;
    float dr = dinv[r];
    uint4 iu = ((const uint4*)(fini16 + (size_t)node * FDH))[t];
    float nr = normf[node];
    const u8* tab = (const u8*)g8 + ((size_t)(ui ? n1 : 0) << 7) + (t << 3);
    GATHER8(tab)
    float2 i01 = unpackbf2(iu.x), i23 = unpackbf2(iu.y);
    float2 i45 = unpackbf2(iu.z), i67 = unpackbf2(iu.w);
    float v0 = (dr * a0 + RCC * i01.x) * 0.5f;
    float v1 = (dr * a1 + RCC * i01.y) * 0.5f;
    float v2 = (dr * a2 + RCC * i23.x) * 0.5f;
    float v3 = (dr * a3 + RCC * i23.y) * 0.5f;
    float v4 = (dr * a4 + RCC * i45.x) * 0.5f;
    float v5 = (dr * a5 + RCC * i45.y) * 0.5f;
    float v6 = (dr * a6 + RCC * i67.x) * 0.5f;
    float v7 = (dr * a7 + RCC * i67.y) * 0.5f;
    float sq = v0*v0 + v1*v1 + v2*v2 + v3*v3 + v4*v4 + v5*v5 + v6*v6 + v7*v7;
#pragma unroll
    for (int off = 8; off > 0; off >>= 1) sq += __shfl_xor(sq, off);
    float inv = 1.0f / fmaxf(sqrtf(sq), 1e-12f);
    v0 *= inv; v1 *= inv; v2 *= inv; v3 *= inv;
    v4 *= inv; v5 *= inv; v6 *= inv; v7 *= inv;
    if (sub == 0) {
        uint4 fa;
        fa.x = packbf2(fmaf(i01.x, nr, v0), fmaf(i01.y, nr, v1));
        fa.y = packbf2(fmaf(i23.x, nr, v2), fmaf(i23.y, nr, v3));
        fa.z = packbf2(fmaf(i45.x, nr, v4), fmaf(i45.y, nr, v5));
        fa.w = packbf2(fmaf(i67.x, nr, v6), fmaf(i67.y, nr, v7));
        ((uint4*)(facc16 + (size_t)r * FDH))[t] = fa;
        int xa = __builtin_amdgcn_cvt_pk_fp8_f32(v0 * dr, v1 * dr, 0, false);
        xa = __builtin_amdgcn_cvt_pk_fp8_f32(v2 * dr, v3 * dr, xa, true);
        int xb = __builtin_amdgcn_cvt_pk_fp8_f32(v4 * dr, v5 * dr, 0, false);
        xb = __builtin_amdgcn_cvt_pk_fp8_f32(v6 * dr, v7 * dr, xb, true);
        ((uint2*)(fX8 + (size_t)r * 32))[t] = make_uint2((uint)xa, (uint)xb);
    }
}

// ---------------- Layer 2: pure gather from pre-scaled fp8 fX8 (2 rows/wave) ----------
__global__ void spmm_L2(const int* __restrict__ rowptr, const int* __restrict__ cols,
                        const float* __restrict__ dinv, const uint* __restrict__ fini16,
                        const uint* __restrict__ facc16, const uint* __restrict__ fX8,
                        uint* __restrict__ items16, float* __restrict__ outp,
                        int n1, int NU, int NB, int n12) {
    int wv = (blockIdx.x * blockDim.x + threadIdx.x) >> 6;
    int lane = threadIdx.x & 63;
    int hw = lane >> 5, l31 = lane & 31, sub = (lane >> 4) & 1, t = lane & 15;
    int r = 2 * wv + hw;
    if (r >= n12) return;
    int s = rowptr[r], e = rowptr[r + 1];
    bool ui = (r >= n1);
    int node = ui ? ((r - n1 < NU) ? (r - n1) : (r - n1 + NB)) : r;
    float dr = dinv[r];
    uint4 iu = ((const uint4*)(fini16 + (size_t)node * FDH))[t];
    uint4 au = ((const uint4*)(facc16 + (size_t)r * FDH))[t];
    const u8* tab = (const u8*)fX8 + ((size_t)(ui ? n1 : 0) << 7) + (t << 3);
    GATHER8(tab)
    float2 i01 = unpackbf2(iu.x), i23 = unpackbf2(iu.y);
    float2 i45 = unpackbf2(iu.z), i67 = unpackbf2(iu.w);
    float v0 = (dr * a0 + RCC * i01.x) * (1.0f / 3.0f);
    float v1 = (dr * a1 + RCC * i01.y) * (1.0f / 3.0f);
    float v2 = (dr * a2 + RCC * i23.x) * (1.0f / 3.0f);
    float v3 = (dr * a3 + RCC * i23.y) * (1.0f / 3.0f);
    float v4 = (dr * a4 + RCC * i45.x) * (1.0f / 3.0f);
    float v5 = (dr * a5 + RCC * i45.y) * (1.0f / 3.0f);
    float v6 = (dr * a6 + RCC * i67.x) * (1.0f / 3.0f);
    float v7 = (dr * a7 + RCC * i67.y) * (1.0f / 3.0f);
    float sq = v0*v0 + v1*v1 + v2*v2 + v3*v3 + v4*v4 + v5*v5 + v6*v6 + v7*v7;
#pragma unroll
    for (int off = 8; off > 0; off >>= 1) sq += __shfl_xor(sq, off);
    float inv = 1.0f / fmaxf(sqrtf(sq), 1e-12f);
    v0 *= inv; v1 *= inv; v2 *= inv; v3 *= inv;
    v4 *= inv; v5 *= inv; v6 *= inv; v7 *= inv;
    float2 a01 = unpackbf2(au.x), a23 = unpackbf2(au.y);
    float2 a45 = unpackbf2(au.z), a67 = unpackbf2(au.w);
    float n0 = a01.x + v0, n1v = a01.y + v1, n2v = a23.x + v2, n3 = a23.y + v3;
    float n4 = a45.x + v4, n5 = a45.y + v5, n6 = a67.x + v6, n7 = a67.y + v7;
    if (sub == 0) {
        if (!ui) {
            size_t dst = (r < NU) ? (size_t)(NU + r) : (size_t)(2 * NU + NB + (r - NU));
            float* orow = outp + dst * FD;
            ((float4*)orow)[2 * t]     = make_float4(n0, n1v, n2v, n3);
            ((float4*)orow)[2 * t + 1] = make_float4(n4, n5, n6, n7);
        } else {
            int l = r - n1;
            if (l < NU) {
                float* orow = outp + (size_t)l * FD;
                ((float4*)orow)[2 * t]     = make_float4(n0, n1v, n2v, n3);
                ((float4*)orow)[2 * t + 1] = make_float4(n4, n5, n6, n7);
            } else {
                uint4 it;
                it.x = packbf2(n0, n1v);
                it.y = packbf2(n2v, n3);
                it.z = packbf2(n4, n5);
                it.w = packbf2(n6, n7);
                ((uint4*)(items16 + (size_t)(l - NU) * FDH))[t] = it;
            }
        }
    }
}

// ---------------- BI gather from bf16 items (2 rows/wave, packed col+wt) --------------
#define FMA8(XU, W) { float2 _f;                                                 \
    _f = unpackbf2((XU).x); a0 = fmaf(W, _f.x, a0); a1 = fmaf(W, _f.y, a1);      \
    _f = unpackbf2((XU).y); a2 = fmaf(W, _f.x, a2); a3 = fmaf(W, _f.y, a3);      \
    _f = unpackbf2((XU).z); a4 = fmaf(W, _f.x, a4); a5 = fmaf(W, _f.y, a5);      \
    _f = unpackbf2((XU).w); a6 = fmaf(W, _f.x, a6); a7 = fmaf(W, _f.y, a7); }

__global__ void bi_gather(const int* __restrict__ rowptr, const int2* __restrict__ bi2,
                          int S1, const uint* __restrict__ items16,
                          float* __restrict__ outb, int nb) {
    int wv = (blockIdx.x * blockDim.x + threadIdx.x) >> 6;
    int lane = threadIdx.x & 63;
    int hw = lane >> 5, l31 = lane & 31, sub = (lane >> 4) & 1, t = lane & 15;
    int r = 2 * wv + hw;
    if (r >= nb) return;
    int s = rowptr[r], e = rowptr[r + 1];
    const u8* tab = (const u8*)items16 + (t << 4);
    float a0=0.f,a1=0.f,a2=0.f,a3=0.f,a4=0.f,a5=0.f,a6=0.f,a7=0.f;
    int base = lane & 32;
    for (int cs = s; cs < e; cs += 32) {
        int cnt = e - cs; if (cnt > 32) cnt = 32;
        int2 cv = (l31 < cnt) ? bi2[cs + l31 - S1] : make_int2(0, 0);
        int p = 0;
        for (; 2 * p + 8 <= cnt; p += 4) {
            int o0 = __shfl(cv.x, base + 2 * p + sub);
            int o1 = __shfl(cv.x, base + 2 * p + 2 + sub);
            int o2 = __shfl(cv.x, base + 2 * p + 4 + sub);
            int o3 = __shfl(cv.x, base + 2 * p + 6 + sub);
            float w0 = __int_as_float(__shfl(cv.y, base + 2 * p + sub));
            float w1 = __int_as_float(__shfl(cv.y, base + 2 * p + 2 + sub));
            float w2 = __int_as_float(__shfl(cv.y, base + 2 * p + 4 + sub));
            float w3 = __int_as_float(__shfl(cv.y, base + 2 * p + 6 + sub));
            uint4 x0 = *(const uint4*)(tab + o0);
            uint4 x1 = *(const uint4*)(tab + o1);
            uint4 x2 = *(const uint4*)(tab + o2);
            uint4 x3 = *(const uint4*)(tab + o3);
            FMA8(x0, w0) FMA8(x1, w1) FMA8(x2, w2) FMA8(x3, w3)
        }
        for (; 2 * p + 2 <= cnt; ++p) {
            int o = __shfl(cv.x, base + 2 * p + sub);
            float wt = __int_as_float(__shfl(cv.y, base + 2 * p + sub));
            uint4 x = *(const uint4*)(tab + o);
            FMA8(x, wt)
        }
        if (2 * p < cnt) {
            int o = __shfl(cv.x, base + 2 * p);
            float wt = __int_as_float(__shfl(cv.y, base + 2 * p));
            if (sub == 0) { uint4 x = *(const uint4*)(tab + o); FMA8(x, wt) }
        }
    }
    a0 += __shfl_xor(a0, 16); a1 += __shfl_xor(a1, 16);
    a2 += __shfl_xor(a2, 16); a3 += __shfl_xor(a3, 16);
    a4 += __shfl_xor(a4, 16); a5 += __shfl_xor(a5, 16);
    a6 += __shfl_xor(a6, 16); a7 += __shfl_xor(a7, 16);
    if (sub == 0) {
        float* orow = outb + (size_t)r * FD;
        ((float4*)orow)[2 * t]     = make_float4(a0, a1, a2, a3);
        ((float4*)orow)[2 * t + 1] = make_float4(a4, a5, a6, a7);
    }
}

extern "C" void kernel_launch(void* const* d_in, const int* in_sizes, int n_in,
                              void* d_out, int out_size, void* d_ws, size_t ws_size,
                              hipStream_t stream) {
    const float* users   = (const float*)d_in[0];
    const float* bundles = (const float*)d_in[1];
    const float* items   = (const float*)d_in[2];
    const float* bi_vals = (const float*)d_in[3];
    const int* ub_u = (const int*)d_in[4];
    const int* ub_b = (const int*)d_in[5];
    const int* ui_u = (const int*)d_in[6];
    const int* ui_i = (const int*)d_in[7];
    const int* bi_b = (const int*)d_in[8];
    const int* bi_i = (const int*)d_in[9];

    const int NU = in_sizes[0] / FD;
    const int NB = in_sizes[1] / FD;
    const int NI = in_sizes[2] / FD;
    const int E_BI = in_sizes[3];
    const int E_UB = in_sizes[4];
    const int E_UI = in_sizes[6];
    float* out = (float*)d_out;

    const int n1 = NU + NB, n2 = NU + NI;
    const int n12 = n1 + n2;
    const int NT = NU + NB + NI;
    const int NN = n12 + NB;                        // total CSR rows
    const int S1 = 2 * E_UB + 2 * E_UI;             // first BI slot / BI rowptr base
    const int TOT = S1 + E_BI;                      // total CSR entries
    const int ETOT = E_UB + E_UI + E_BI;

    // ---- workspace layout ----
    uint* fini16   = (uint*)d_ws;                          // NT*FDH uints
    uint* facc16   = fini16 + (size_t)NT * FDH;            // n12*FDH uints
    uint* items16  = facc16 + (size_t)n12 * FDH;           // NI*FDH uints
    u16* g8        = (u16*)(items16 + (size_t)NI * FDH);   // n12*FDH u16
    uint* fX8      = (uint*)(g8 + (size_t)n12 * FDH);      // n12*32 uints
    float* normf   = (float*)(fX8 + (size_t)n12 * 32);     // NT
    float* dinv    = normf + NT;                           // n12
    int* deg       = (int*)(dinv + n12);                   // NN+1
    int* rowptr    = deg + (NN + 1);                       // NN+1
    int* head      = rowptr + (NN + 1);                    // NN
    int* bsum      = head + NN;                            // 512
    int* cols      = bsum + 512;                           // S1
    int2* bi2      = (int2*)((((size_t)(cols + S1)) + 15) & ~(size_t)15);   // E_BI int2
    int2* pairLL   = (int2*)((((size_t)(bi2 + E_BI)) + 15) & ~(size_t)15);  // TOT int2

    dim3 blk(256);
    auto rows_grid  = [](int n) { return dim3((unsigned)((n + 3) / 4)); };
    auto rows2_grid = [](int n) { return dim3((unsigned)((n + 7) / 8)); };
    auto thr_grid   = [](int n) { return dim3((unsigned)((n + 255) / 256)); };

    // ---- linked-list CSR build (one atomic pass) + fused feature prep ----
    hipMemsetAsync(head, 0xFF, (size_t)NN * 4, stream);    // head = -1
    int nblk_edges = (ETOT + 255) / 256;
    int nblk_prep  = (NT + 3) / 4;
    passA<<<dim3((unsigned)(nblk_edges + nblk_prep)), blk, 0, stream>>>(
        ub_u, ub_b, ui_u, ui_i, bi_b, bi_i, users, bundles, items,
        E_UB, E_UI, E_BI, NU, NB, n1, n2, NT, nblk_edges,
        head, pairLL, fini16, normf);
    passB<<<thr_grid(NN + 1), blk, 0, stream>>>(head, pairLL, NN, n12, deg, dinv);
    {
        int nelem = NN + 1;
        int nblk = (nelem + SCAN_ELEMS - 1) / SCAN_ELEMS;
        scan_a<<<dim3((unsigned)nblk), dim3(SCAN_TPB), 0, stream>>>(deg, rowptr, bsum, nelem);
        scan_b<<<dim3(1), dim3(512), 0, stream>>>(bsum, nblk);
        scan_c<<<dim3((unsigned)nblk), dim3(SCAN_TPB), 0, stream>>>(rowptr, bsum, nelem);
    }
    {
        int nblkC = (NN + 255) / 256;
        int nblkG = (n12 + 3) / 4;
        passC_conv<<<dim3((unsigned)(nblkC + nblkG)), blk, 0, stream>>>(
            head, pairLL, rowptr, bi_vals, NN, n12, S1, cols, bi2,
            fini16, normf, dinv, n1, NU, NB, g8, nblkC);
    }

    // ---- Layer 1 (UB + UI fused, 2 rows/wave fp8 gather) ----
    spmm_L1<<<rows2_grid(n12), blk, 0, stream>>>(rowptr, cols, dinv, normf,
                                                 fini16, g8, facc16, fX8, n1, NU, NB, n12);
    // ---- Layer 2 (UB + UI fused, 2 rows/wave fp8 gather) + writeout ----
    spmm_L2<<<rows2_grid(n12), blk, 0, stream>>>(rowptr, cols, dinv, fini16,
                                                 facc16, fX8, items16, out, n1, NU, NB, n12);
    // ---- BI aggregation ----
    bi_gather<<<rows2_grid(NB), blk, 0, stream>>>(rowptr + n12, bi2, S1, items16,
        out + (size_t)2 * NU * FD, NB);
}